// Round 6
// baseline (1305.724 us; speedup 1.0000x reference)
//
#include <hip/hip_runtime.h>
#include <hip/hip_bf16.h>

#define N_NODES   50000
#define N_EDGES   800000
#define NUM_GRAPHS 256
#define IN_DIM    128
#define HD        64      // hidden dim of SAGE layers
#define EPS       1e-5f

// ---------------- diagnostics: encode ws_size into output ----------------
__global__ void k_diag(float* __restrict__ out, int n, float v) {
    int t = blockIdx.x * 256 + threadIdx.x;
    if (t < n) out[t] = v;
}

// ---------------- degree / graph counts ----------------
__global__ void k_edge_count(const int* __restrict__ dst, float* __restrict__ cnt) {
    int e = blockIdx.x * 256 + threadIdx.x;
    if (e < N_EDGES) atomicAdd(&cnt[dst[e]], 1.0f);
}

__global__ void k_node_gcnt(const int* __restrict__ batch, float* __restrict__ gcnt) {
    int i = blockIdx.x * 256 + threadIdx.x;
    if (i < N_NODES) atomicAdd(&gcnt[batch[i]], 1.0f);
}

// ---------------- transform: B = h_in @ Wl   [N, HD] ----------------
__global__ void k_xform(const float* __restrict__ h_in, const float* __restrict__ Wl,
                        float* __restrict__ B, int in_dim) {
    int t = blockIdx.x * 256 + threadIdx.x;
    int i = t >> 6, j = t & 63;
    if (i >= N_NODES) return;
    const float* hr = h_in + (long)i * in_dim;
    float s = 0.f;
    #pragma unroll 4
    for (int k = 0; k < in_dim; k++) s += hr[k] * Wl[k * HD + j];
    B[(long)i * HD + j] = s;
}

// ---------------- edge scatter (mean numerator) ----------------
__global__ void k_scatter(const int* __restrict__ src, const int* __restrict__ dst,
                          const float* __restrict__ B, float* __restrict__ C) {
    long t = (long)blockIdx.x * 256 + threadIdx.x;
    int e = (int)(t >> 6), j = (int)(t & 63);
    if (e >= N_EDGES) return;
    int s = src[e], d = dst[e];
    atomicAdd(&C[(long)d * HD + j], B[(long)s * HD + j]);
}

// ---- combine (in-place on C): C = C/max(cnt,1) + h_in@Wr + bl ----
__global__ void k_combine(float* __restrict__ C, const float* __restrict__ cnt,
                          const float* __restrict__ h_in, const float* __restrict__ Wr,
                          const float* __restrict__ bl, int in_dim) {
    int t = blockIdx.x * 256 + threadIdx.x;
    int i = t >> 6, j = t & 63;
    if (i >= N_NODES) return;
    const float* hr = h_in + (long)i * in_dim;
    float s = 0.f;
    #pragma unroll 4
    for (int k = 0; k < in_dim; k++) s += hr[k] * Wr[k * HD + j];
    float c = fmaxf(cnt[i], 1.0f);
    long idx = (long)i * HD + j;
    C[idx] = C[idx] / c + s + bl[j];
}

// ---------------- global mean pool ----------------
__global__ void k_pool(const int* __restrict__ batch, const float* __restrict__ h,
                       float* __restrict__ pool) {
    int t = blockIdx.x * 256 + threadIdx.x;
    int i = t >> 6;
    if (i >= N_NODES) return;
    atomicAdd(&pool[(long)batch[i] * HD + (t & 63)], h[t]);
}

__global__ void k_pooldiv(const float* __restrict__ pool, const float* __restrict__ gcnt,
                          float* __restrict__ c) {
    int t = blockIdx.x * 256 + threadIdx.x;
    if (t >= NUM_GRAPHS * HD) return;
    int g = t >> 6;
    c[t] = pool[t] / fmaxf(gcnt[g], 1.0f);
}

// ---------------- MLP head ----------------
__global__ void k_head_gemm(const float* __restrict__ A, const float* __restrict__ W,
                            const float* __restrict__ b, float* __restrict__ out,
                            int K, int N) {
    int t = blockIdx.x * 256 + threadIdx.x;
    if (t >= NUM_GRAPHS * N) return;
    int i = t / N, j = t % N;
    float s = b[j];
    for (int k = 0; k < K; k++) s += A[i * K + k] * W[k * N + j];
    out[t] = s;
}

__device__ __forceinline__ float block_sum_256(float v, float* red) {
    #pragma unroll
    for (int o = 32; o > 0; o >>= 1) v += __shfl_down(v, o);
    int lane = threadIdx.x & 63, wid = threadIdx.x >> 6;
    if (lane == 0) red[wid] = v;
    __syncthreads();
    if (threadIdx.x == 0) red[0] = red[0] + red[1] + red[2] + red[3];
    __syncthreads();
    float s = red[0];
    __syncthreads();
    return s;
}

// one block per column j (grid = N), one thread per row (block = 256)
__global__ void k_bn_tanh(float* __restrict__ X, const float* __restrict__ g,
                          const float* __restrict__ be, int N) {
    __shared__ float red[4];
    int j = blockIdx.x, i = threadIdx.x;
    float v = X[i * N + j];
    float mean = block_sum_256(v, red) * (1.0f / NUM_GRAPHS);
    float d = v - mean;
    float var = block_sum_256(d * d, red) * (1.0f / NUM_GRAPHS);
    float y = d * rsqrtf(var + EPS) * g[j] + be[j];
    X[i * N + j] = tanhf(y);
}

// final: out = A(256x64) @ W(64x10) + b, fp32 out
__global__ void k_final(const float* __restrict__ A, const float* __restrict__ W,
                        const float* __restrict__ b, float* __restrict__ out) {
    int t = blockIdx.x * 256 + threadIdx.x;
    if (t >= NUM_GRAPHS * 10) return;
    int i = t / 10, j = t % 10;
    float s = b[j];
    #pragma unroll
    for (int k = 0; k < 64; k++) s += A[i * 64 + k] * W[k * 10 + j];
    out[t] = s;
}

extern "C" void kernel_launch(void* const* d_in, const int* in_sizes, int n_in,
                              void* d_out, int out_size, void* d_ws, size_t ws_size,
                              hipStream_t stream) {
    const float* x     = (const float*)d_in[0];
    const int*   ei    = (const int*) d_in[1];
    const int*   batch = (const int*) d_in[2];
    const float *W1l = (const float*)d_in[3],  *b1l = (const float*)d_in[4],  *W1r = (const float*)d_in[5];
    const float *W2l = (const float*)d_in[6],  *b2l = (const float*)d_in[7],  *W2r = (const float*)d_in[8];
    const float *W3l = (const float*)d_in[9],  *b3l = (const float*)d_in[10], *W3r = (const float*)d_in[11];
    const float *lin1_w = (const float*)d_in[12], *lin1_b = (const float*)d_in[13];
    const float *g1 = (const float*)d_in[14], *be1 = (const float*)d_in[15];
    const float *lin2_w = (const float*)d_in[16], *lin2_b = (const float*)d_in[17];
    const float *g2 = (const float*)d_in[18], *be2 = (const float*)d_in[19];
    const float *lin3_w = (const float*)d_in[20], *lin3_b = (const float*)d_in[21];
    const float *g3 = (const float*)d_in[22], *be3 = (const float*)d_in[23];
    const float *lin4_w = (const float*)d_in[24], *lin4_b = (const float*)d_in[25];

    const int* srcp = ei;
    const int* dstp = ei + N_EDGES;

    // workspace layout (floats) — total 9,797,760 f = 39,191,040 B (~37.4 MB)
    const long NF = (long)N_NODES * HD;           // 3,200,000
    float* ws   = (float*)d_ws;
    float* cnt  = ws;                             // 50,048
    float* B    = cnt  + 50048;                   // 3,200,000  (messages)
    float* C0   = B    + NF;                      // 3,200,000  (agg / h1 / h3)
    float* D    = C0   + NF;                      // 3,200,000  (agg / h2)
    float* pool = D    + NF;                      // 16,384
    float* gcnt = pool + NUM_GRAPHS * HD;         // 256
    float* cb   = gcnt + 256;                     // 16,384
    float* buf1 = cb   + NUM_GRAPHS * HD;         // 65,536
    float* buf2 = buf1 + NUM_GRAPHS * 256;        // 32,768
    float* buf3 = buf2 + NUM_GRAPHS * 128;        // 16,384

    const size_t NEED = (size_t)(50048 + 3 * NF + 16384 + 256 + 16384 + 65536 + 32768 + 16384) * 4;
    if (ws_size < NEED) {
        k_diag<<<(out_size + 255) / 256, 256, 0, stream>>>((float*)d_out, out_size,
                                                           (float)(ws_size >> 20));
        return;
    }

    const int TB = 256;
    const int gNE = (N_EDGES + TB - 1) / TB;
    const int gNN = (N_NODES + TB - 1) / TB;
    const int gNF = (int)((NF + TB - 1) / TB);                   // 12500
    const int gEF = (int)(((long)N_EDGES * HD + TB - 1) / TB);   // 200000

    hipMemsetAsync(cnt, 0, 50000 * sizeof(float), stream);
    hipMemsetAsync(C0, 0, NF * sizeof(float), stream);
    hipMemsetAsync(pool, 0, (NUM_GRAPHS * HD + 256) * sizeof(float), stream);

    k_edge_count<<<gNE, TB, 0, stream>>>(dstp, cnt);
    k_node_gcnt<<<gNN, TB, 0, stream>>>(batch, gcnt);

    // ---- SAGE layer 1: x(128) -> h1 in C0 ----
    k_xform<<<gNF, TB, 0, stream>>>(x, W1l, B, IN_DIM);
    k_scatter<<<gEF, TB, 0, stream>>>(srcp, dstp, B, C0);
    k_combine<<<gNF, TB, 0, stream>>>(C0, cnt, x, W1r, b1l, IN_DIM);

    // ---- SAGE layer 2: h1(C0) -> h2 in D ----
    hipMemsetAsync(D, 0, NF * sizeof(float), stream);
    k_xform<<<gNF, TB, 0, stream>>>(C0, W2l, B, HD);
    k_scatter<<<gEF, TB, 0, stream>>>(srcp, dstp, B, D);
    k_combine<<<gNF, TB, 0, stream>>>(D, cnt, C0, W2r, b2l, HD);

    // ---- SAGE layer 3: h2(D) -> h3 in C0 ----
    hipMemsetAsync(C0, 0, NF * sizeof(float), stream);
    k_xform<<<gNF, TB, 0, stream>>>(D, W3l, B, HD);
    k_scatter<<<gEF, TB, 0, stream>>>(srcp, dstp, B, C0);
    k_combine<<<gNF, TB, 0, stream>>>(C0, cnt, D, W3r, b3l, HD);

    // ---- global mean pool ----
    k_pool<<<gNF, TB, 0, stream>>>(batch, C0, pool);
    k_pooldiv<<<(NUM_GRAPHS * HD + TB - 1) / TB, TB, 0, stream>>>(pool, gcnt, cb);

    // ---- MLP head ----
    k_head_gemm<<<(NUM_GRAPHS * 256 + TB - 1) / TB, TB, 0, stream>>>(cb, lin1_w, lin1_b, buf1, 64, 256);
    k_bn_tanh<<<256, TB, 0, stream>>>(buf1, g1, be1, 256);
    k_head_gemm<<<(NUM_GRAPHS * 128 + TB - 1) / TB, TB, 0, stream>>>(buf1, lin2_w, lin2_b, buf2, 256, 128);
    k_bn_tanh<<<128, TB, 0, stream>>>(buf2, g2, be2, 128);
    // K=128 here (buf2 is 256x128, lin3_w is 128x64) — was wrongly 256 in R0–R4
    k_head_gemm<<<(NUM_GRAPHS * 64 + TB - 1) / TB, TB, 0, stream>>>(buf2, lin3_w, lin3_b, buf3, 128, 64);
    k_bn_tanh<<<64, TB, 0, stream>>>(buf3, g3, be3, 64);
    k_final<<<(NUM_GRAPHS * 10 + TB - 1) / TB, TB, 0, stream>>>(buf3, lin4_w, lin4_b, (float*)d_out);
}

// Round 7
// 848.204 us; speedup vs baseline: 1.5394x; 1.5394x over previous
//
#include <hip/hip_runtime.h>
#include <hip/hip_bf16.h>

#define N_NODES   50000
#define N_EDGES   800000
#define NUM_GRAPHS 256
#define IN_DIM    128
#define HD        64
#define EPS       1e-5f

// ---------------- diagnostics: encode ws_size into output ----------------
__global__ void k_diag(float* __restrict__ out, int n, float v) {
    int t = blockIdx.x * 256 + threadIdx.x;
    if (t < n) out[t] = v;
}

// ---------------- CSR build ----------------
__global__ void k_count(const int* __restrict__ dst, int* __restrict__ cnti) {
    int e = blockIdx.x * 256 + threadIdx.x;
    if (e < N_EDGES) atomicAdd(&cnti[dst[e]], 1);
}

// single block, 1024 threads: exclusive prefix sum of cnti -> off[0..N_NODES]
__global__ void k_scan(const int* __restrict__ cnti, int* __restrict__ off) {
    __shared__ int wsum[16];
    __shared__ int base;
    int lane = threadIdx.x & 63, wid = threadIdx.x >> 6;
    if (threadIdx.x == 0) base = 0;
    __syncthreads();
    for (int c = 0; c < N_NODES; c += 1024) {
        int idx = c + threadIdx.x;
        int v = (idx < N_NODES) ? cnti[idx] : 0;
        int s = v;
        #pragma unroll
        for (int o = 1; o < 64; o <<= 1) {
            int u = __shfl_up(s, o);
            if (lane >= o) s += u;
        }
        if (lane == 63) wsum[wid] = s;
        __syncthreads();
        if (wid == 0 && lane < 16) {
            int w = wsum[lane];
            #pragma unroll
            for (int o = 1; o < 16; o <<= 1) {
                int u = __shfl_up(w, o);
                if (lane >= o) w += u;
            }
            wsum[lane] = w;
        }
        __syncthreads();
        int wbase = (wid > 0) ? wsum[wid - 1] : 0;
        int total = wsum[15];
        if (idx < N_NODES) off[idx] = base + wbase + s - v;
        __syncthreads();
        if (threadIdx.x == 0) base += total;
        __syncthreads();
    }
    if (threadIdx.x == 0) off[N_NODES] = base;
}

__global__ void k_fill(const int* __restrict__ src, const int* __restrict__ dst,
                       const int* __restrict__ off, int* __restrict__ tmp,
                       int* __restrict__ nbr) {
    int e = blockIdx.x * 256 + threadIdx.x;
    if (e >= N_EDGES) return;
    int d = dst[e];
    int p = atomicAdd(&tmp[d], 1);
    nbr[off[d] + p] = src[e];
}

// ---- fused transform: B = X@Wl ; C = X@Wr + bl   (one wave per node) ----
__global__ void k_xform2(const float* __restrict__ X, const float* __restrict__ Wl,
                         const float* __restrict__ Wr, const float* __restrict__ bl,
                         float* __restrict__ B, float* __restrict__ C, int K) {
    int t = blockIdx.x * 256 + threadIdx.x;
    int i = t >> 6, j = t & 63;
    if (i >= N_NODES) return;
    const float* xr = X + (long)i * K;
    float sl = 0.f, sr = 0.f;
    for (int k = 0; k < K; k += 4) {
        float4 h4 = *(const float4*)(xr + k);
        sl += h4.x * Wl[(k + 0) * HD + j];  sr += h4.x * Wr[(k + 0) * HD + j];
        sl += h4.y * Wl[(k + 1) * HD + j];  sr += h4.y * Wr[(k + 1) * HD + j];
        sl += h4.z * Wl[(k + 2) * HD + j];  sr += h4.z * Wr[(k + 2) * HD + j];
        sl += h4.w * Wl[(k + 3) * HD + j];  sr += h4.w * Wr[(k + 3) * HD + j];
    }
    B[(long)i * HD + j] = sl;
    C[(long)i * HD + j] = sr + bl[j];
}

// ---- CSR gather: C[i,:] += mean_{s in nbr(i)} B[s,:]   (one wave per node) ----
__global__ void k_gather(const int* __restrict__ off, const int* __restrict__ nbr,
                         const float* __restrict__ B, float* __restrict__ C) {
    int t = blockIdx.x * 256 + threadIdx.x;
    int i = t >> 6, j = t & 63;
    if (i >= N_NODES) return;
    int beg = off[i], end = off[i + 1];
    float s0 = 0.f, s1 = 0.f, s2 = 0.f, s3 = 0.f;
    for (int base = beg; base < end; base += 64) {
        int idx = base + j;
        int nv = (idx < end) ? nbr[idx] : 0;
        int m = min(64, end - base);
        int tt = 0;
        for (; tt + 4 <= m; tt += 4) {
            int n0 = __shfl(nv, tt + 0);
            int n1 = __shfl(nv, tt + 1);
            int n2 = __shfl(nv, tt + 2);
            int n3 = __shfl(nv, tt + 3);
            s0 += B[(long)n0 * HD + j];
            s1 += B[(long)n1 * HD + j];
            s2 += B[(long)n2 * HD + j];
            s3 += B[(long)n3 * HD + j];
        }
        for (; tt < m; ++tt) {
            int nb = __shfl(nv, tt);
            s0 += B[(long)nb * HD + j];
        }
    }
    int deg = end - beg;
    float inv = 1.0f / (float)max(deg, 1);
    C[(long)i * HD + j] += (s0 + s1 + s2 + s3) * inv;
}

// ---------------- global mean pool ----------------
__global__ void k_node_gcnt(const int* __restrict__ batch, float* __restrict__ gcnt) {
    int i = blockIdx.x * 256 + threadIdx.x;
    if (i < N_NODES) atomicAdd(&gcnt[batch[i]], 1.0f);
}

__global__ void k_pool(const int* __restrict__ batch, const float* __restrict__ h,
                       float* __restrict__ pool) {
    int t = blockIdx.x * 256 + threadIdx.x;
    int i = t >> 6;
    if (i >= N_NODES) return;
    atomicAdd(&pool[(long)batch[i] * HD + (t & 63)], h[t]);
}

__global__ void k_pooldiv(const float* __restrict__ pool, const float* __restrict__ gcnt,
                          float* __restrict__ c) {
    int t = blockIdx.x * 256 + threadIdx.x;
    if (t >= NUM_GRAPHS * HD) return;
    int g = t >> 6;
    c[t] = pool[t] / fmaxf(gcnt[g], 1.0f);
}

// ---------------- fused head: out = tanh(BN(A@W + b)) ----------------
__device__ __forceinline__ float block_sum_256(float v, float* red) {
    #pragma unroll
    for (int o = 32; o > 0; o >>= 1) v += __shfl_down(v, o);
    int lane = threadIdx.x & 63, wid = threadIdx.x >> 6;
    if (lane == 0) red[wid] = v;
    __syncthreads();
    if (threadIdx.x == 0) red[0] = red[0] + red[1] + red[2] + red[3];
    __syncthreads();
    float s = red[0];
    __syncthreads();
    return s;
}

// grid = N columns, block = 256 rows
__global__ void k_lin_bn_tanh(const float* __restrict__ A, const float* __restrict__ W,
                              const float* __restrict__ b, const float* __restrict__ g,
                              const float* __restrict__ be, float* __restrict__ out,
                              int K, int N) {
    __shared__ float red[4];
    int j = blockIdx.x, i = threadIdx.x;
    const float* ar = A + i * K;
    float s = b[j];
    for (int k = 0; k < K; k++) s += ar[k] * W[k * N + j];
    float mean = block_sum_256(s, red) * (1.0f / NUM_GRAPHS);
    float d = s - mean;
    float var = block_sum_256(d * d, red) * (1.0f / NUM_GRAPHS);
    out[i * N + j] = tanhf(d * rsqrtf(var + EPS) * g[j] + be[j]);
}

// final: out = A(256x64) @ W(64x10) + b
__global__ void k_final(const float* __restrict__ A, const float* __restrict__ W,
                        const float* __restrict__ b, float* __restrict__ out) {
    int t = blockIdx.x * 256 + threadIdx.x;
    if (t >= NUM_GRAPHS * 10) return;
    int i = t / 10, j = t % 10;
    float s = b[j];
    #pragma unroll
    for (int k = 0; k < 64; k++) s += A[i * 64 + k] * W[k * 10 + j];
    out[t] = s;
}

extern "C" void kernel_launch(void* const* d_in, const int* in_sizes, int n_in,
                              void* d_out, int out_size, void* d_ws, size_t ws_size,
                              hipStream_t stream) {
    const float* x     = (const float*)d_in[0];
    const int*   ei    = (const int*) d_in[1];
    const int*   batch = (const int*) d_in[2];
    const float *W1l = (const float*)d_in[3],  *b1l = (const float*)d_in[4],  *W1r = (const float*)d_in[5];
    const float *W2l = (const float*)d_in[6],  *b2l = (const float*)d_in[7],  *W2r = (const float*)d_in[8];
    const float *W3l = (const float*)d_in[9],  *b3l = (const float*)d_in[10], *W3r = (const float*)d_in[11];
    const float *lin1_w = (const float*)d_in[12], *lin1_b = (const float*)d_in[13];
    const float *g1 = (const float*)d_in[14], *be1 = (const float*)d_in[15];
    const float *lin2_w = (const float*)d_in[16], *lin2_b = (const float*)d_in[17];
    const float *g2 = (const float*)d_in[18], *be2 = (const float*)d_in[19];
    const float *lin3_w = (const float*)d_in[20], *lin3_b = (const float*)d_in[21];
    const float *g3 = (const float*)d_in[22], *be3 = (const float*)d_in[23];
    const float *lin4_w = (const float*)d_in[24], *lin4_b = (const float*)d_in[25];

    const int* srcp = ei;
    const int* dstp = ei + N_EDGES;

    // ---- workspace layout ----
    const long NF = (long)N_NODES * HD;              // 3,200,000
    char* wsb  = (char*)d_ws;
    int*  cnti = (int*)wsb;                          // 50,048
    int*  tmp  = cnti + 50048;                       // 50,048
    int*  off  = tmp  + 50048;                       // 50,056 (N+1 used)
    int*  nbr  = off  + 50056;                       // 800,000
    float* B   = (float*)(nbr + 800000);             // 3,200,000
    float* H1  = B   + NF;                           // 3,200,000
    float* H2  = H1  + NF;                           // 3,200,000
    float* pool= H2  + NF;                           // 16,384
    float* gcnt= pool+ NUM_GRAPHS * HD;              // 256
    float* cb  = gcnt+ 256;                          // 16,384
    float* m1  = cb  + NUM_GRAPHS * HD;              // 65,536
    float* m2  = m1  + NUM_GRAPHS * 256;             // 32,768
    float* m3  = m2  + NUM_GRAPHS * 128;             // 16,384
    float* endp= m3  + NUM_GRAPHS * 64;

    const size_t NEED = (size_t)((char*)endp - wsb);
    if (ws_size < NEED) {
        k_diag<<<(out_size + 255) / 256, 256, 0, stream>>>((float*)d_out, out_size,
                                                           (float)(ws_size >> 20));
        return;
    }

    const int TB = 256;
    const int gNE = (N_EDGES + TB - 1) / TB;
    const int gNN = (N_NODES + TB - 1) / TB;
    const int gNF = (int)((NF + TB - 1) / TB);       // 12500

    hipMemsetAsync(cnti, 0, 2 * 50048 * sizeof(int), stream);   // cnti + tmp
    hipMemsetAsync(pool, 0, (NUM_GRAPHS * HD + 256) * sizeof(float), stream);

    // ---- CSR build (reused by all 3 layers) ----
    k_count<<<gNE, TB, 0, stream>>>(dstp, cnti);
    k_scan<<<1, 1024, 0, stream>>>(cnti, off);
    k_fill<<<gNE, TB, 0, stream>>>(srcp, dstp, off, tmp, nbr);

    k_node_gcnt<<<gNN, TB, 0, stream>>>(batch, gcnt);

    // ---- SAGE layer 1: x(128) -> H1 ----
    k_xform2<<<gNF, TB, 0, stream>>>(x, W1l, W1r, b1l, B, H1, IN_DIM);
    k_gather<<<gNF, TB, 0, stream>>>(off, nbr, B, H1);

    // ---- SAGE layer 2: H1 -> H2 ----
    k_xform2<<<gNF, TB, 0, stream>>>(H1, W2l, W2r, b2l, B, H2, HD);
    k_gather<<<gNF, TB, 0, stream>>>(off, nbr, B, H2);

    // ---- SAGE layer 3: H2 -> H1 ----
    k_xform2<<<gNF, TB, 0, stream>>>(H2, W3l, W3r, b3l, B, H1, HD);
    k_gather<<<gNF, TB, 0, stream>>>(off, nbr, B, H1);

    // ---- global mean pool ----
    k_pool<<<gNF, TB, 0, stream>>>(batch, H1, pool);
    k_pooldiv<<<(NUM_GRAPHS * HD + TB - 1) / TB, TB, 0, stream>>>(pool, gcnt, cb);

    // ---- MLP head (fused GEMM+BN+tanh per layer) ----
    k_lin_bn_tanh<<<256, TB, 0, stream>>>(cb, lin1_w, lin1_b, g1, be1, m1, 64, 256);
    k_lin_bn_tanh<<<128, TB, 0, stream>>>(m1, lin2_w, lin2_b, g2, be2, m2, 256, 128);
    k_lin_bn_tanh<<< 64, TB, 0, stream>>>(m2, lin3_w, lin3_b, g3, be3, m3, 128, 64);
    k_final<<<(NUM_GRAPHS * 10 + TB - 1) / TB, TB, 0, stream>>>(m3, lin4_w, lin4_b, (float*)d_out);
}

// Round 8
// 710.148 us; speedup vs baseline: 1.8387x; 1.1944x over previous
//
#include <hip/hip_runtime.h>
#include <hip/hip_bf16.h>

#define N_NODES   50000
#define N_EDGES   800000
#define NUM_GRAPHS 256
#define IN_DIM    128
#define HD        64
#define EPS       1e-5f

// ---------------- diagnostics ----------------
__global__ void k_diag(float* __restrict__ out, int n, float v) {
    int t = blockIdx.x * 256 + threadIdx.x;
    if (t < n) out[t] = v;
}

// ---------------- CSR build ----------------
__global__ void k_count(const int* __restrict__ dst, int* __restrict__ cnti) {
    int e = blockIdx.x * 256 + threadIdx.x;
    if (e < N_EDGES) atomicAdd(&cnti[dst[e]], 1);
}

// single block, 1024 threads: exclusive prefix sum of cnti -> off[0..N_NODES]
__global__ void k_scan(const int* __restrict__ cnti, int* __restrict__ off) {
    __shared__ int wsum[16];
    __shared__ int base;
    int lane = threadIdx.x & 63, wid = threadIdx.x >> 6;
    if (threadIdx.x == 0) base = 0;
    __syncthreads();
    for (int c = 0; c < N_NODES; c += 1024) {
        int idx = c + threadIdx.x;
        int v = (idx < N_NODES) ? cnti[idx] : 0;
        int s = v;
        #pragma unroll
        for (int o = 1; o < 64; o <<= 1) {
            int u = __shfl_up(s, o);
            if (lane >= o) s += u;
        }
        if (lane == 63) wsum[wid] = s;
        __syncthreads();
        if (wid == 0 && lane < 16) {
            int w = wsum[lane];
            #pragma unroll
            for (int o = 1; o < 16; o <<= 1) {
                int u = __shfl_up(w, o);
                if (lane >= o) w += u;
            }
            wsum[lane] = w;
        }
        __syncthreads();
        int wbase = (wid > 0) ? wsum[wid - 1] : 0;
        int total = wsum[15];
        if (idx < N_NODES) off[idx] = base + wbase + s - v;
        __syncthreads();
        if (threadIdx.x == 0) base += total;
        __syncthreads();
    }
    if (threadIdx.x == 0) off[N_NODES] = base;
}

__global__ void k_fill(const int* __restrict__ src, const int* __restrict__ dst,
                       const int* __restrict__ off, int* __restrict__ tmp,
                       int* __restrict__ nbr) {
    int e = blockIdx.x * 256 + threadIdx.x;
    if (e >= N_EDGES) return;
    int d = dst[e];
    int p = atomicAdd(&tmp[d], 1);
    nbr[off[d] + p] = src[e];
}

// ---- fused transform, 8 nodes per wave: B = X@Wl ; C = X@Wr + bl ----
// Weights fetched once per wave per k-chunk, reused across 8 nodes.
template <int K>
__global__ __launch_bounds__(256) void k_xform2(
        const float* __restrict__ X, const float* __restrict__ Wl,
        const float* __restrict__ Wr, const float* __restrict__ bl,
        float* __restrict__ B, float* __restrict__ C) {
    const int NPW = 8;
    int gt = blockIdx.x * 256 + threadIdx.x;
    int wave = gt >> 6, j = gt & 63;
    long base = (long)wave * NPW;
    if (base >= N_NODES) return;     // 50000 % 8 == 0: active waves are always full
    float accB[NPW], accC[NPW];
    #pragma unroll
    for (int n = 0; n < NPW; n++) { accB[n] = 0.f; accC[n] = 0.f; }
    const float* Xb = X + base * K;
    for (int kc = 0; kc < K; kc += 4) {
        float wl0 = Wl[(kc + 0) * HD + j], wr0 = Wr[(kc + 0) * HD + j];
        float wl1 = Wl[(kc + 1) * HD + j], wr1 = Wr[(kc + 1) * HD + j];
        float wl2 = Wl[(kc + 2) * HD + j], wr2 = Wr[(kc + 2) * HD + j];
        float wl3 = Wl[(kc + 3) * HD + j], wr3 = Wr[(kc + 3) * HD + j];
        #pragma unroll
        for (int n = 0; n < NPW; n++) {
            float4 xv = *(const float4*)(Xb + (long)n * K + kc);
            accB[n] = fmaf(xv.x, wl0, accB[n]);
            accC[n] = fmaf(xv.x, wr0, accC[n]);
            accB[n] = fmaf(xv.y, wl1, accB[n]);
            accC[n] = fmaf(xv.y, wr1, accC[n]);
            accB[n] = fmaf(xv.z, wl2, accB[n]);
            accC[n] = fmaf(xv.z, wr2, accC[n]);
            accB[n] = fmaf(xv.w, wl3, accB[n]);
            accC[n] = fmaf(xv.w, wr3, accC[n]);
        }
    }
    float bb = bl[j];
    #pragma unroll
    for (int n = 0; n < NPW; n++) {
        long i = base + n;
        B[i * HD + j] = accB[n];
        C[i * HD + j] = accC[n] + bb;
    }
}

// ---- CSR gather: C[i,:] += mean_{s in nbr(i)} B[s,:]  (one wave per node) ----
__global__ void k_gather(const int* __restrict__ off, const int* __restrict__ nbr,
                         const float* __restrict__ B, float* __restrict__ C) {
    int t = blockIdx.x * 256 + threadIdx.x;
    int i = t >> 6, j = t & 63;
    if (i >= N_NODES) return;
    int beg = off[i], end = off[i + 1];
    float s0 = 0.f, s1 = 0.f, s2 = 0.f, s3 = 0.f;
    float s4 = 0.f, s5 = 0.f, s6 = 0.f, s7 = 0.f;
    for (int base = beg; base < end; base += 64) {
        int idx = base + j;
        int nv = (idx < end) ? nbr[idx] : 0;
        int m = min(64, end - base);
        int tt = 0;
        for (; tt + 8 <= m; tt += 8) {
            int n0 = __shfl(nv, tt + 0);
            int n1 = __shfl(nv, tt + 1);
            int n2 = __shfl(nv, tt + 2);
            int n3 = __shfl(nv, tt + 3);
            int n4 = __shfl(nv, tt + 4);
            int n5 = __shfl(nv, tt + 5);
            int n6 = __shfl(nv, tt + 6);
            int n7 = __shfl(nv, tt + 7);
            s0 += B[(long)n0 * HD + j];
            s1 += B[(long)n1 * HD + j];
            s2 += B[(long)n2 * HD + j];
            s3 += B[(long)n3 * HD + j];
            s4 += B[(long)n4 * HD + j];
            s5 += B[(long)n5 * HD + j];
            s6 += B[(long)n6 * HD + j];
            s7 += B[(long)n7 * HD + j];
        }
        for (; tt < m; ++tt) {
            int nb = __shfl(nv, tt);
            s0 += B[(long)nb * HD + j];
        }
    }
    int deg = end - beg;
    float inv = 1.0f / (float)max(deg, 1);
    C[(long)i * HD + j] += ((s0 + s1) + (s2 + s3) + ((s4 + s5) + (s6 + s7))) * inv;
}

// ---------------- global mean pool ----------------
__global__ void k_node_gcnt(const int* __restrict__ batch, float* __restrict__ gcnt) {
    int i = blockIdx.x * 256 + threadIdx.x;
    if (i < N_NODES) atomicAdd(&gcnt[batch[i]], 1.0f);
}

__global__ void k_pool(const int* __restrict__ batch, const float* __restrict__ h,
                       float* __restrict__ pool) {
    int t = blockIdx.x * 256 + threadIdx.x;
    int i = t >> 6;
    if (i >= N_NODES) return;
    atomicAdd(&pool[(long)batch[i] * HD + (t & 63)], h[t]);
}

__global__ void k_pooldiv(const float* __restrict__ pool, const float* __restrict__ gcnt,
                          float* __restrict__ c) {
    int t = blockIdx.x * 256 + threadIdx.x;
    if (t >= NUM_GRAPHS * HD) return;
    int g = t >> 6;
    c[t] = pool[t] / fmaxf(gcnt[g], 1.0f);
}

// ---------------- fused head: out = tanh(BN(A@W + b)) ----------------
__device__ __forceinline__ float block_sum_256(float v, float* red) {
    #pragma unroll
    for (int o = 32; o > 0; o >>= 1) v += __shfl_down(v, o);
    int lane = threadIdx.x & 63, wid = threadIdx.x >> 6;
    if (lane == 0) red[wid] = v;
    __syncthreads();
    if (threadIdx.x == 0) red[0] = red[0] + red[1] + red[2] + red[3];
    __syncthreads();
    float s = red[0];
    __syncthreads();
    return s;
}

// grid = N columns, block = 256 rows
__global__ void k_lin_bn_tanh(const float* __restrict__ A, const float* __restrict__ W,
                              const float* __restrict__ b, const float* __restrict__ g,
                              const float* __restrict__ be, float* __restrict__ out,
                              int K, int N) {
    __shared__ float red[4];
    int j = blockIdx.x, i = threadIdx.x;
    const float* ar = A + i * K;
    float s = b[j];
    for (int k = 0; k < K; k++) s += ar[k] * W[k * N + j];
    float mean = block_sum_256(s, red) * (1.0f / NUM_GRAPHS);
    float d = s - mean;
    float var = block_sum_256(d * d, red) * (1.0f / NUM_GRAPHS);
    out[i * N + j] = tanhf(d * rsqrtf(var + EPS) * g[j] + be[j]);
}

// final: out = A(256x64) @ W(64x10) + b
__global__ void k_final(const float* __restrict__ A, const float* __restrict__ W,
                        const float* __restrict__ b, float* __restrict__ out) {
    int t = blockIdx.x * 256 + threadIdx.x;
    if (t >= NUM_GRAPHS * 10) return;
    int i = t / 10, j = t % 10;
    float s = b[j];
    #pragma unroll
    for (int k = 0; k < 64; k++) s += A[i * 64 + k] * W[k * 10 + j];
    out[t] = s;
}

extern "C" void kernel_launch(void* const* d_in, const int* in_sizes, int n_in,
                              void* d_out, int out_size, void* d_ws, size_t ws_size,
                              hipStream_t stream) {
    const float* x     = (const float*)d_in[0];
    const int*   ei    = (const int*) d_in[1];
    const int*   batch = (const int*) d_in[2];
    const float *W1l = (const float*)d_in[3],  *b1l = (const float*)d_in[4],  *W1r = (const float*)d_in[5];
    const float *W2l = (const float*)d_in[6],  *b2l = (const float*)d_in[7],  *W2r = (const float*)d_in[8];
    const float *W3l = (const float*)d_in[9],  *b3l = (const float*)d_in[10], *W3r = (const float*)d_in[11];
    const float *lin1_w = (const float*)d_in[12], *lin1_b = (const float*)d_in[13];
    const float *g1 = (const float*)d_in[14], *be1 = (const float*)d_in[15];
    const float *lin2_w = (const float*)d_in[16], *lin2_b = (const float*)d_in[17];
    const float *g2 = (const float*)d_in[18], *be2 = (const float*)d_in[19];
    const float *lin3_w = (const float*)d_in[20], *lin3_b = (const float*)d_in[21];
    const float *g3 = (const float*)d_in[22], *be3 = (const float*)d_in[23];
    const float *lin4_w = (const float*)d_in[24], *lin4_b = (const float*)d_in[25];

    const int* srcp = ei;
    const int* dstp = ei + N_EDGES;

    // ---- workspace layout ----
    const long NF = (long)N_NODES * HD;              // 3,200,000
    char* wsb  = (char*)d_ws;
    int*  cnti = (int*)wsb;                          // 50,048
    int*  tmp  = cnti + 50048;                       // 50,048
    int*  off  = tmp  + 50048;                       // 50,056 (N+1 used)
    int*  nbr  = off  + 50056;                       // 800,000
    float* B   = (float*)(nbr + 800000);             // 3,200,000
    float* H1  = B   + NF;                           // 3,200,000
    float* H2  = H1  + NF;                           // 3,200,000
    float* pool= H2  + NF;                           // 16,384
    float* gcnt= pool+ NUM_GRAPHS * HD;              // 256
    float* cb  = gcnt+ 256;                          // 16,384
    float* m1  = cb  + NUM_GRAPHS * HD;              // 65,536
    float* m2  = m1  + NUM_GRAPHS * 256;             // 32,768
    float* m3  = m2  + NUM_GRAPHS * 128;             // 16,384
    float* endp= m3  + NUM_GRAPHS * 64;

    const size_t NEED = (size_t)((char*)endp - wsb);
    if (ws_size < NEED) {
        k_diag<<<(out_size + 255) / 256, 256, 0, stream>>>((float*)d_out, out_size,
                                                           (float)(ws_size >> 20));
        return;
    }

    const int TB = 256;
    const int gNE = (N_EDGES + TB - 1) / TB;
    const int gNN = (N_NODES + TB - 1) / TB;
    const int gNF = (int)((NF + TB - 1) / TB);       // 12500 (64 thr/node kernels)
    const int gXW = (N_NODES / 8 * 64 + TB - 1) / TB; // 8 nodes/wave transform: 1563

    hipMemsetAsync(cnti, 0, 2 * 50048 * sizeof(int), stream);   // cnti + tmp
    hipMemsetAsync(pool, 0, (NUM_GRAPHS * HD + 256) * sizeof(float), stream);

    // ---- CSR build (reused by all 3 layers) ----
    k_count<<<gNE, TB, 0, stream>>>(dstp, cnti);
    k_scan<<<1, 1024, 0, stream>>>(cnti, off);
    k_fill<<<gNE, TB, 0, stream>>>(srcp, dstp, off, tmp, nbr);

    k_node_gcnt<<<gNN, TB, 0, stream>>>(batch, gcnt);

    // ---- SAGE layer 1: x(128) -> H1 ----
    k_xform2<IN_DIM><<<gXW, TB, 0, stream>>>(x, W1l, W1r, b1l, B, H1);
    k_gather<<<gNF, TB, 0, stream>>>(off, nbr, B, H1);

    // ---- SAGE layer 2: H1 -> H2 ----
    k_xform2<HD><<<gXW, TB, 0, stream>>>(H1, W2l, W2r, b2l, B, H2);
    k_gather<<<gNF, TB, 0, stream>>>(off, nbr, B, H2);

    // ---- SAGE layer 3: H2 -> H1 ----
    k_xform2<HD><<<gXW, TB, 0, stream>>>(H2, W3l, W3r, b3l, B, H1);
    k_gather<<<gNF, TB, 0, stream>>>(off, nbr, B, H1);

    // ---- global mean pool ----
    k_pool<<<gNF, TB, 0, stream>>>(batch, H1, pool);
    k_pooldiv<<<(NUM_GRAPHS * HD + TB - 1) / TB, TB, 0, stream>>>(pool, gcnt, cb);

    // ---- MLP head (fused GEMM+BN+tanh per layer) ----
    k_lin_bn_tanh<<<256, TB, 0, stream>>>(cb, lin1_w, lin1_b, g1, be1, m1, 64, 256);
    k_lin_bn_tanh<<<128, TB, 0, stream>>>(m1, lin2_w, lin2_b, g2, be2, m2, 256, 128);
    k_lin_bn_tanh<<< 64, TB, 0, stream>>>(m2, lin3_w, lin3_b, g3, be3, m3, 128, 64);
    k_final<<<(NUM_GRAPHS * 10 + TB - 1) / TB, TB, 0, stream>>>(m3, lin4_w, lin4_b, (float*)d_out);
}

// Round 9
// 664.873 us; speedup vs baseline: 1.9639x; 1.0681x over previous
//
#include <hip/hip_runtime.h>
#include <hip/hip_bf16.h>

#define N_NODES   50000
#define N_EDGES   800000
#define NUM_GRAPHS 256
#define IN_DIM    128
#define HD        64
#define EPS       1e-5f

// ---------------- diagnostics ----------------
__global__ void k_diag(float* __restrict__ out, int n, float v) {
    int t = blockIdx.x * 256 + threadIdx.x;
    if (t < n) out[t] = v;
}

// ---------------- CSR build ----------------
__global__ void k_count(const int* __restrict__ dst, int* __restrict__ cnti) {
    int e = blockIdx.x * 256 + threadIdx.x;
    if (e < N_EDGES) atomicAdd(&cnti[dst[e]], 1);
}

// single block, 1024 threads: exclusive prefix sum of cnti -> off[0..N_NODES]
__global__ void k_scan(const int* __restrict__ cnti, int* __restrict__ off) {
    __shared__ int wsum[16];
    __shared__ int base;
    int lane = threadIdx.x & 63, wid = threadIdx.x >> 6;
    if (threadIdx.x == 0) base = 0;
    __syncthreads();
    for (int c = 0; c < N_NODES; c += 1024) {
        int idx = c + threadIdx.x;
        int v = (idx < N_NODES) ? cnti[idx] : 0;
        int s = v;
        #pragma unroll
        for (int o = 1; o < 64; o <<= 1) {
            int u = __shfl_up(s, o);
            if (lane >= o) s += u;
        }
        if (lane == 63) wsum[wid] = s;
        __syncthreads();
        if (wid == 0 && lane < 16) {
            int w = wsum[lane];
            #pragma unroll
            for (int o = 1; o < 16; o <<= 1) {
                int u = __shfl_up(w, o);
                if (lane >= o) w += u;
            }
            wsum[lane] = w;
        }
        __syncthreads();
        int wbase = (wid > 0) ? wsum[wid - 1] : 0;
        int total = wsum[15];
        if (idx < N_NODES) off[idx] = base + wbase + s - v;
        __syncthreads();
        if (threadIdx.x == 0) base += total;
        __syncthreads();
    }
    if (threadIdx.x == 0) off[N_NODES] = base;
}

__global__ void k_fill(const int* __restrict__ src, const int* __restrict__ dst,
                       const int* __restrict__ off, int* __restrict__ tmp,
                       int* __restrict__ nbr) {
    int e = blockIdx.x * 256 + threadIdx.x;
    if (e >= N_EDGES) return;
    int d = dst[e];
    int p = atomicAdd(&tmp[d], 1);
    nbr[off[d] + p] = src[e];
}

// ---- graph boundaries in sorted batch: goff[g] = lower_bound(batch, g) ----
__global__ void k_gbounds(const int* __restrict__ batch, int* __restrict__ goff) {
    int g = blockIdx.x * blockDim.x + threadIdx.x;
    if (g > NUM_GRAPHS) return;
    int lo = 0, hi = N_NODES;
    while (lo < hi) {
        int mid = (lo + hi) >> 1;
        if (batch[mid] < g) lo = mid + 1; else hi = mid;
    }
    goff[g] = lo;
}

// ---- fused transform, 8 nodes per wave: B = X@Wl ; C = X@Wr + bl ----
template <int K>
__global__ __launch_bounds__(256) void k_xform2(
        const float* __restrict__ X, const float* __restrict__ Wl,
        const float* __restrict__ Wr, const float* __restrict__ bl,
        float* __restrict__ B, float* __restrict__ C) {
    const int NPW = 8;
    int gt = blockIdx.x * 256 + threadIdx.x;
    int wave = gt >> 6, j = gt & 63;
    long base = (long)wave * NPW;
    if (base >= N_NODES) return;
    float accB[NPW], accC[NPW];
    #pragma unroll
    for (int n = 0; n < NPW; n++) { accB[n] = 0.f; accC[n] = 0.f; }
    const float* Xb = X + base * K;
    for (int kc = 0; kc < K; kc += 4) {
        float wl0 = Wl[(kc + 0) * HD + j], wr0 = Wr[(kc + 0) * HD + j];
        float wl1 = Wl[(kc + 1) * HD + j], wr1 = Wr[(kc + 1) * HD + j];
        float wl2 = Wl[(kc + 2) * HD + j], wr2 = Wr[(kc + 2) * HD + j];
        float wl3 = Wl[(kc + 3) * HD + j], wr3 = Wr[(kc + 3) * HD + j];
        #pragma unroll
        for (int n = 0; n < NPW; n++) {
            float4 xv = *(const float4*)(Xb + (long)n * K + kc);
            accB[n] = fmaf(xv.x, wl0, accB[n]);
            accC[n] = fmaf(xv.x, wr0, accC[n]);
            accB[n] = fmaf(xv.y, wl1, accB[n]);
            accC[n] = fmaf(xv.y, wr1, accC[n]);
            accB[n] = fmaf(xv.z, wl2, accB[n]);
            accC[n] = fmaf(xv.z, wr2, accC[n]);
            accB[n] = fmaf(xv.w, wl3, accB[n]);
            accC[n] = fmaf(xv.w, wr3, accC[n]);
        }
    }
    float bb = bl[j];
    #pragma unroll
    for (int n = 0; n < NPW; n++) {
        long i = base + n;
        B[i * HD + j] = accB[n];
        C[i * HD + j] = accC[n] + bb;
    }
}

// ---- CSR gather: C[i,:] += mean_{s in nbr(i)} B[s,:]  (one wave per node) ----
__global__ void k_gather(const int* __restrict__ off, const int* __restrict__ nbr,
                         const float* __restrict__ B, float* __restrict__ C) {
    int t = blockIdx.x * 256 + threadIdx.x;
    int i = t >> 6, j = t & 63;
    if (i >= N_NODES) return;
    int beg = off[i], end = off[i + 1];
    float s0 = 0.f, s1 = 0.f, s2 = 0.f, s3 = 0.f;
    float s4 = 0.f, s5 = 0.f, s6 = 0.f, s7 = 0.f;
    for (int base = beg; base < end; base += 64) {
        int idx = base + j;
        int nv = (idx < end) ? nbr[idx] : 0;
        int m = min(64, end - base);
        int tt = 0;
        for (; tt + 8 <= m; tt += 8) {
            int n0 = __shfl(nv, tt + 0);
            int n1 = __shfl(nv, tt + 1);
            int n2 = __shfl(nv, tt + 2);
            int n3 = __shfl(nv, tt + 3);
            int n4 = __shfl(nv, tt + 4);
            int n5 = __shfl(nv, tt + 5);
            int n6 = __shfl(nv, tt + 6);
            int n7 = __shfl(nv, tt + 7);
            s0 += B[(long)n0 * HD + j];
            s1 += B[(long)n1 * HD + j];
            s2 += B[(long)n2 * HD + j];
            s3 += B[(long)n3 * HD + j];
            s4 += B[(long)n4 * HD + j];
            s5 += B[(long)n5 * HD + j];
            s6 += B[(long)n6 * HD + j];
            s7 += B[(long)n7 * HD + j];
        }
        for (; tt < m; ++tt) {
            int nb = __shfl(nv, tt);
            s0 += B[(long)nb * HD + j];
        }
    }
    int deg = end - beg;
    float inv = 1.0f / (float)max(deg, 1);
    C[(long)i * HD + j] += ((s0 + s1) + (s2 + s3) + ((s4 + s5) + (s6 + s7))) * inv;
}

// ---- global mean pool via sorted-batch segments (no atomics) ----
// grid = NUM_GRAPHS, block = 256 (4 row-lanes x 64 cols)
__global__ void k_pool2(const int* __restrict__ goff, const float* __restrict__ h,
                        float* __restrict__ cb) {
    __shared__ float red[4][64];
    int g = blockIdx.x;
    int j = threadIdx.x & 63, r = threadIdx.x >> 6;
    int beg = goff[g], end = goff[g + 1];
    float s = 0.f;
    for (int n = beg + r; n < end; n += 4) s += h[(long)n * HD + j];
    red[r][j] = s;
    __syncthreads();
    if (r == 0) {
        float tot = (red[0][j] + red[1][j]) + (red[2][j] + red[3][j]);
        int cnt = end - beg;
        cb[g * HD + j] = tot / (float)max(cnt, 1);
    }
}

// ---- head GEMM: lanes = columns (W coalesced, A broadcast) ----
// NN columns; 256/NN row-groups per block; 8 rows per group.
template <int NN>
__global__ void k_head_gemm2(const float* __restrict__ A, const float* __restrict__ W,
                             const float* __restrict__ b, float* __restrict__ out,
                             int K) {
    const int RG = 256 / NN;
    const int ROWS = 8;
    int j = threadIdx.x & (NN - 1);
    int rg = threadIdx.x / NN;
    int r0 = (blockIdx.x * RG + rg) * ROWS;
    float s[ROWS];
    float bj = b[j];
    #pragma unroll
    for (int r = 0; r < ROWS; r++) s[r] = bj;
    for (int k = 0; k < K; k++) {
        float wk = W[k * NN + j];
        #pragma unroll
        for (int r = 0; r < ROWS; r++)
            s[r] = fmaf(A[(r0 + r) * K + k], wk, s[r]);
    }
    #pragma unroll
    for (int r = 0; r < ROWS; r++) out[(r0 + r) * NN + j] = s[r];
}

// ---- BN(train-stats) + tanh, one block per column ----
__device__ __forceinline__ float block_sum_256(float v, float* red) {
    #pragma unroll
    for (int o = 32; o > 0; o >>= 1) v += __shfl_down(v, o);
    int lane = threadIdx.x & 63, wid = threadIdx.x >> 6;
    if (lane == 0) red[wid] = v;
    __syncthreads();
    if (threadIdx.x == 0) red[0] = red[0] + red[1] + red[2] + red[3];
    __syncthreads();
    float s = red[0];
    __syncthreads();
    return s;
}

__global__ void k_bn_tanh2(float* __restrict__ X, const float* __restrict__ g,
                           const float* __restrict__ be, int N) {
    __shared__ float red[4];
    int j = blockIdx.x, i = threadIdx.x;
    float v = X[i * N + j];
    float mean = block_sum_256(v, red) * (1.0f / NUM_GRAPHS);
    float d = v - mean;
    float var = block_sum_256(d * d, red) * (1.0f / NUM_GRAPHS);
    X[i * N + j] = tanhf(d * rsqrtf(var + EPS) * g[j] + be[j]);
}

// final: out = A(256x64) @ W(64x10) + b
__global__ void k_final(const float* __restrict__ A, const float* __restrict__ W,
                        const float* __restrict__ b, float* __restrict__ out) {
    int t = blockIdx.x * 256 + threadIdx.x;
    if (t >= NUM_GRAPHS * 10) return;
    int i = t / 10, j = t % 10;
    float s = b[j];
    #pragma unroll
    for (int k = 0; k < 64; k++) s += A[i * 64 + k] * W[k * 10 + j];
    out[t] = s;
}

extern "C" void kernel_launch(void* const* d_in, const int* in_sizes, int n_in,
                              void* d_out, int out_size, void* d_ws, size_t ws_size,
                              hipStream_t stream) {
    const float* x     = (const float*)d_in[0];
    const int*   ei    = (const int*) d_in[1];
    const int*   batch = (const int*) d_in[2];
    const float *W1l = (const float*)d_in[3],  *b1l = (const float*)d_in[4],  *W1r = (const float*)d_in[5];
    const float *W2l = (const float*)d_in[6],  *b2l = (const float*)d_in[7],  *W2r = (const float*)d_in[8];
    const float *W3l = (const float*)d_in[9],  *b3l = (const float*)d_in[10], *W3r = (const float*)d_in[11];
    const float *lin1_w = (const float*)d_in[12], *lin1_b = (const float*)d_in[13];
    const float *g1 = (const float*)d_in[14], *be1 = (const float*)d_in[15];
    const float *lin2_w = (const float*)d_in[16], *lin2_b = (const float*)d_in[17];
    const float *g2 = (const float*)d_in[18], *be2 = (const float*)d_in[19];
    const float *lin3_w = (const float*)d_in[20], *lin3_b = (const float*)d_in[21];
    const float *g3 = (const float*)d_in[22], *be3 = (const float*)d_in[23];
    const float *lin4_w = (const float*)d_in[24], *lin4_b = (const float*)d_in[25];

    const int* srcp = ei;
    const int* dstp = ei + N_EDGES;

    // ---- workspace layout ----
    const long NF = (long)N_NODES * HD;              // 3,200,000
    char* wsb  = (char*)d_ws;
    int*  cnti = (int*)wsb;                          // 50,048
    int*  tmp  = cnti + 50048;                       // 50,048
    int*  off  = tmp  + 50048;                       // 50,056 (N+1 used)
    int*  nbr  = off  + 50056;                       // 800,000
    int*  goff = nbr  + 800000;                      // 320 (257 used)
    float* B   = (float*)(goff + 320);               // 3,200,000
    float* H1  = B   + NF;                           // 3,200,000
    float* H2  = H1  + NF;                           // 3,200,000
    float* cb  = H2  + NF;                           // 16,384
    float* m1  = cb  + NUM_GRAPHS * HD;              // 65,536
    float* m2  = m1  + NUM_GRAPHS * 256;             // 32,768
    float* m3  = m2  + NUM_GRAPHS * 128;             // 16,384
    float* endp= m3  + NUM_GRAPHS * 64;

    const size_t NEED = (size_t)((char*)endp - wsb);
    if (ws_size < NEED) {
        k_diag<<<(out_size + 255) / 256, 256, 0, stream>>>((float*)d_out, out_size,
                                                           (float)(ws_size >> 20));
        return;
    }

    const int TB = 256;
    const int gNE = (N_EDGES + TB - 1) / TB;
    const int gNF = (int)((NF + TB - 1) / TB);        // 12500 (64 thr/node kernels)
    const int gXW = (N_NODES / 8 * 64 + TB - 1) / TB; // 1563

    hipMemsetAsync(cnti, 0, 2 * 50048 * sizeof(int), stream);   // cnti + tmp

    // ---- CSR build (reused by all 3 layers) ----
    k_count<<<gNE, TB, 0, stream>>>(dstp, cnti);
    k_scan<<<1, 1024, 0, stream>>>(cnti, off);
    k_fill<<<gNE, TB, 0, stream>>>(srcp, dstp, off, tmp, nbr);

    k_gbounds<<<1, 512, 0, stream>>>(batch, goff);

    // ---- SAGE layer 1: x(128) -> H1 ----
    k_xform2<IN_DIM><<<gXW, TB, 0, stream>>>(x, W1l, W1r, b1l, B, H1);
    k_gather<<<gNF, TB, 0, stream>>>(off, nbr, B, H1);

    // ---- SAGE layer 2: H1 -> H2 ----
    k_xform2<HD><<<gXW, TB, 0, stream>>>(H1, W2l, W2r, b2l, B, H2);
    k_gather<<<gNF, TB, 0, stream>>>(off, nbr, B, H2);

    // ---- SAGE layer 3: H2 -> H1 ----
    k_xform2<HD><<<gXW, TB, 0, stream>>>(H2, W3l, W3r, b3l, B, H1);
    k_gather<<<gNF, TB, 0, stream>>>(off, nbr, B, H1);

    // ---- global mean pool (segment reduction over sorted batch) ----
    k_pool2<<<NUM_GRAPHS, TB, 0, stream>>>(goff, H1, cb);

    // ---- MLP head ----
    k_head_gemm2<256><<<32, TB, 0, stream>>>(cb, lin1_w, lin1_b, m1, 64);
    k_bn_tanh2<<<256, TB, 0, stream>>>(m1, g1, be1, 256);
    k_head_gemm2<128><<<16, TB, 0, stream>>>(m1, lin2_w, lin2_b, m2, 256);
    k_bn_tanh2<<<128, TB, 0, stream>>>(m2, g2, be2, 128);
    k_head_gemm2<64><<<8, TB, 0, stream>>>(m2, lin3_w, lin3_b, m3, 128);
    k_bn_tanh2<<<64, TB, 0, stream>>>(m3, g3, be3, 64);
    k_final<<<(NUM_GRAPHS * 10 + TB - 1) / TB, TB, 0, stream>>>(m3, lin4_w, lin4_b, (float*)d_out);
}

// Round 10
// 664.686 us; speedup vs baseline: 1.9644x; 1.0003x over previous
//
#include <hip/hip_runtime.h>
#include <hip/hip_bf16.h>

#define N_NODES   50000
#define N_EDGES   800000
#define NUM_GRAPHS 256
#define IN_DIM    128
#define HD        64
#define EPS       1e-5f

// ---------------- diagnostics ----------------
__global__ void k_diag(float* __restrict__ out, int n, float v) {
    int t = blockIdx.x * 256 + threadIdx.x;
    if (t < n) out[t] = v;
}

// ---------------- CSR build ----------------
__global__ void k_count(const int* __restrict__ dst, int* __restrict__ cnti) {
    int e = blockIdx.x * 256 + threadIdx.x;
    if (e < N_EDGES) atomicAdd(&cnti[dst[e]], 1);
}

// single block, 1024 threads: exclusive prefix sum of cnti -> off[0..N_NODES]
__global__ void k_scan(const int* __restrict__ cnti, int* __restrict__ off) {
    __shared__ int wsum[16];
    __shared__ int base;
    int lane = threadIdx.x & 63, wid = threadIdx.x >> 6;
    if (threadIdx.x == 0) base = 0;
    __syncthreads();
    for (int c = 0; c < N_NODES; c += 1024) {
        int idx = c + threadIdx.x;
        int v = (idx < N_NODES) ? cnti[idx] : 0;
        int s = v;
        #pragma unroll
        for (int o = 1; o < 64; o <<= 1) {
            int u = __shfl_up(s, o);
            if (lane >= o) s += u;
        }
        if (lane == 63) wsum[wid] = s;
        __syncthreads();
        if (wid == 0 && lane < 16) {
            int w = wsum[lane];
            #pragma unroll
            for (int o = 1; o < 16; o <<= 1) {
                int u = __shfl_up(w, o);
                if (lane >= o) w += u;
            }
            wsum[lane] = w;
        }
        __syncthreads();
        int wbase = (wid > 0) ? wsum[wid - 1] : 0;
        int total = wsum[15];
        if (idx < N_NODES) off[idx] = base + wbase + s - v;
        __syncthreads();
        if (threadIdx.x == 0) base += total;
        __syncthreads();
    }
    if (threadIdx.x == 0) off[N_NODES] = base;
}

__global__ void k_fill(const int* __restrict__ src, const int* __restrict__ dst,
                       const int* __restrict__ off, int* __restrict__ tmp,
                       int* __restrict__ nbr) {
    int e = blockIdx.x * 256 + threadIdx.x;
    if (e >= N_EDGES) return;
    int d = dst[e];
    int p = atomicAdd(&tmp[d], 1);
    nbr[off[d] + p] = src[e];
}

// ---- graph boundaries in sorted batch ----
__global__ void k_gbounds(const int* __restrict__ batch, int* __restrict__ goff) {
    int g = blockIdx.x * blockDim.x + threadIdx.x;
    if (g > NUM_GRAPHS) return;
    int lo = 0, hi = N_NODES;
    while (lo < hi) {
        int mid = (lo + hi) >> 1;
        if (batch[mid] < g) lo = mid + 1; else hi = mid;
    }
    goff[g] = lo;
}

// ---- fused transform, 8 nodes per wave: B = X@Wl ; C = X@Wr + bl ----
template <int K>
__global__ __launch_bounds__(256) void k_xform2(
        const float* __restrict__ X, const float* __restrict__ Wl,
        const float* __restrict__ Wr, const float* __restrict__ bl,
        float* __restrict__ B, float* __restrict__ C) {
    const int NPW = 8;
    int gt = blockIdx.x * 256 + threadIdx.x;
    int wave = gt >> 6, j = gt & 63;
    long base = (long)wave * NPW;
    if (base >= N_NODES) return;
    float accB[NPW], accC[NPW];
    #pragma unroll
    for (int n = 0; n < NPW; n++) { accB[n] = 0.f; accC[n] = 0.f; }
    const float* Xb = X + base * K;
    for (int kc = 0; kc < K; kc += 4) {
        float wl0 = Wl[(kc + 0) * HD + j], wr0 = Wr[(kc + 0) * HD + j];
        float wl1 = Wl[(kc + 1) * HD + j], wr1 = Wr[(kc + 1) * HD + j];
        float wl2 = Wl[(kc + 2) * HD + j], wr2 = Wr[(kc + 2) * HD + j];
        float wl3 = Wl[(kc + 3) * HD + j], wr3 = Wr[(kc + 3) * HD + j];
        #pragma unroll
        for (int n = 0; n < NPW; n++) {
            float4 xv = *(const float4*)(Xb + (long)n * K + kc);
            accB[n] = fmaf(xv.x, wl0, accB[n]);
            accC[n] = fmaf(xv.x, wr0, accC[n]);
            accB[n] = fmaf(xv.y, wl1, accB[n]);
            accC[n] = fmaf(xv.y, wr1, accC[n]);
            accB[n] = fmaf(xv.z, wl2, accB[n]);
            accC[n] = fmaf(xv.z, wr2, accC[n]);
            accB[n] = fmaf(xv.w, wl3, accB[n]);
            accC[n] = fmaf(xv.w, wr3, accC[n]);
        }
    }
    float bb = bl[j];
    #pragma unroll
    for (int n = 0; n < NPW; n++) {
        long i = base + n;
        B[i * HD + j] = accB[n];
        C[i * HD + j] = accC[n] + bb;
    }
}

// ---- CSR gather: C[i,:] += mean_{s in nbr(i)} B[s,:]  (one wave per node) ----
__global__ void k_gather(const int* __restrict__ off, const int* __restrict__ nbr,
                         const float* __restrict__ B, float* __restrict__ C) {
    int t = blockIdx.x * 256 + threadIdx.x;
    int i = t >> 6, j = t & 63;
    if (i >= N_NODES) return;
    int beg = off[i], end = off[i + 1];
    float s0 = 0.f, s1 = 0.f, s2 = 0.f, s3 = 0.f;
    float s4 = 0.f, s5 = 0.f, s6 = 0.f, s7 = 0.f;
    for (int base = beg; base < end; base += 64) {
        int idx = base + j;
        int nv = (idx < end) ? nbr[idx] : 0;
        int m = min(64, end - base);
        int tt = 0;
        for (; tt + 8 <= m; tt += 8) {
            int n0 = __shfl(nv, tt + 0);
            int n1 = __shfl(nv, tt + 1);
            int n2 = __shfl(nv, tt + 2);
            int n3 = __shfl(nv, tt + 3);
            int n4 = __shfl(nv, tt + 4);
            int n5 = __shfl(nv, tt + 5);
            int n6 = __shfl(nv, tt + 6);
            int n7 = __shfl(nv, tt + 7);
            s0 += B[(long)n0 * HD + j];
            s1 += B[(long)n1 * HD + j];
            s2 += B[(long)n2 * HD + j];
            s3 += B[(long)n3 * HD + j];
            s4 += B[(long)n4 * HD + j];
            s5 += B[(long)n5 * HD + j];
            s6 += B[(long)n6 * HD + j];
            s7 += B[(long)n7 * HD + j];
        }
        for (; tt < m; ++tt) {
            int nb = __shfl(nv, tt);
            s0 += B[(long)nb * HD + j];
        }
    }
    int deg = end - beg;
    float inv = 1.0f / (float)max(deg, 1);
    C[(long)i * HD + j] += ((s0 + s1) + (s2 + s3) + ((s4 + s5) + (s6 + s7))) * inv;
}

// ---- global mean pool via sorted-batch segments ----
__global__ void k_pool2(const int* __restrict__ goff, const float* __restrict__ h,
                        float* __restrict__ cb) {
    __shared__ float red[4][64];
    int g = blockIdx.x;
    int j = threadIdx.x & 63, r = threadIdx.x >> 6;
    int beg = goff[g], end = goff[g + 1];
    float s = 0.f;
    for (int n = beg + r; n < end; n += 4) s += h[(long)n * HD + j];
    red[r][j] = s;
    __syncthreads();
    if (r == 0) {
        float tot = (red[0][j] + red[1][j]) + (red[2][j] + red[3][j]);
        int cnt = end - beg;
        cb[g * HD + j] = tot / (float)max(cnt, 1);
    }
}

// ---- head GEMM: thread = 4 rows x 1 col, K unrolled x4, float4 A loads ----
// grid = NN/4 blocks of 256 (total threads = 64 row-groups * NN cols)
template <int NN>
__global__ void k_head_gemm3(const float* __restrict__ A, const float* __restrict__ W,
                             const float* __restrict__ b, float* __restrict__ out,
                             int K) {
    int t = blockIdx.x * 256 + threadIdx.x;
    int j = t % NN;
    int r0 = (t / NN) * 4;
    float s0, s1, s2, s3;
    s0 = s1 = s2 = s3 = b[j];
    for (int k = 0; k < K; k += 4) {
        float w0 = W[(k + 0) * NN + j];
        float w1 = W[(k + 1) * NN + j];
        float w2 = W[(k + 2) * NN + j];
        float w3 = W[(k + 3) * NN + j];
        float4 a0 = *(const float4*)(A + (r0 + 0) * K + k);
        float4 a1 = *(const float4*)(A + (r0 + 1) * K + k);
        float4 a2 = *(const float4*)(A + (r0 + 2) * K + k);
        float4 a3 = *(const float4*)(A + (r0 + 3) * K + k);
        s0 = fmaf(a0.x, w0, s0); s0 = fmaf(a0.y, w1, s0); s0 = fmaf(a0.z, w2, s0); s0 = fmaf(a0.w, w3, s0);
        s1 = fmaf(a1.x, w0, s1); s1 = fmaf(a1.y, w1, s1); s1 = fmaf(a1.z, w2, s1); s1 = fmaf(a1.w, w3, s1);
        s2 = fmaf(a2.x, w0, s2); s2 = fmaf(a2.y, w1, s2); s2 = fmaf(a2.z, w2, s2); s2 = fmaf(a2.w, w3, s2);
        s3 = fmaf(a3.x, w0, s3); s3 = fmaf(a3.y, w1, s3); s3 = fmaf(a3.z, w2, s3); s3 = fmaf(a3.w, w3, s3);
    }
    out[(r0 + 0) * NN + j] = s0;
    out[(r0 + 1) * NN + j] = s1;
    out[(r0 + 2) * NN + j] = s2;
    out[(r0 + 3) * NN + j] = s3;
}

// ---- BN(train-stats)+tanh: block = 4 row-lanes x 64 cols, coalesced ----
// grid = N/64 blocks
__global__ void k_bn_tanh3(float* __restrict__ X, const float* __restrict__ g,
                           const float* __restrict__ be, int N) {
    __shared__ float ssum[4][64], ssq[4][64], sscale[64], smean[64];
    int j = blockIdx.x * 64 + (threadIdx.x & 63);
    int jj = threadIdx.x & 63, rl = threadIdx.x >> 6;
    float sum = 0.f, sq = 0.f;
    for (int r = rl; r < NUM_GRAPHS; r += 4) {
        float v = X[r * N + j];
        sum += v; sq += v * v;
    }
    ssum[rl][jj] = sum; ssq[rl][jj] = sq;
    __syncthreads();
    if (rl == 0) {
        float S = (ssum[0][jj] + ssum[1][jj]) + (ssum[2][jj] + ssum[3][jj]);
        float Q = (ssq[0][jj] + ssq[1][jj]) + (ssq[2][jj] + ssq[3][jj]);
        float mean = S * (1.0f / NUM_GRAPHS);
        float var = Q * (1.0f / NUM_GRAPHS) - mean * mean;
        smean[jj] = mean;
        sscale[jj] = rsqrtf(fmaxf(var, 0.f) + EPS) * g[j];
    }
    __syncthreads();
    float mean = smean[jj], scale = sscale[jj], sh = be[j];
    for (int r = rl; r < NUM_GRAPHS; r += 4) {
        float v = X[r * N + j];
        X[r * N + j] = tanhf((v - mean) * scale + sh);
    }
}

// final: out = A(256x64) @ W(64x10) + b
__global__ void k_final(const float* __restrict__ A, const float* __restrict__ W,
                        const float* __restrict__ b, float* __restrict__ out) {
    int t = blockIdx.x * 256 + threadIdx.x;
    if (t >= NUM_GRAPHS * 10) return;
    int i = t / 10, j = t % 10;
    float s = b[j];
    #pragma unroll
    for (int k = 0; k < 64; k++) s += A[i * 64 + k] * W[k * 10 + j];
    out[t] = s;
}

extern "C" void kernel_launch(void* const* d_in, const int* in_sizes, int n_in,
                              void* d_out, int out_size, void* d_ws, size_t ws_size,
                              hipStream_t stream) {
    const float* x     = (const float*)d_in[0];
    const int*   ei    = (const int*) d_in[1];
    const int*   batch = (const int*) d_in[2];
    const float *W1l = (const float*)d_in[3],  *b1l = (const float*)d_in[4],  *W1r = (const float*)d_in[5];
    const float *W2l = (const float*)d_in[6],  *b2l = (const float*)d_in[7],  *W2r = (const float*)d_in[8];
    const float *W3l = (const float*)d_in[9],  *b3l = (const float*)d_in[10], *W3r = (const float*)d_in[11];
    const float *lin1_w = (const float*)d_in[12], *lin1_b = (const float*)d_in[13];
    const float *g1 = (const float*)d_in[14], *be1 = (const float*)d_in[15];
    const float *lin2_w = (const float*)d_in[16], *lin2_b = (const float*)d_in[17];
    const float *g2 = (const float*)d_in[18], *be2 = (const float*)d_in[19];
    const float *lin3_w = (const float*)d_in[20], *lin3_b = (const float*)d_in[21];
    const float *g3 = (const float*)d_in[22], *be3 = (const float*)d_in[23];
    const float *lin4_w = (const float*)d_in[24], *lin4_b = (const float*)d_in[25];

    const int* srcp = ei;
    const int* dstp = ei + N_EDGES;

    // ---- workspace layout ----
    const long NF = (long)N_NODES * HD;              // 3,200,000
    char* wsb  = (char*)d_ws;
    int*  cnti = (int*)wsb;                          // 50,048
    int*  tmp  = cnti + 50048;                       // 50,048
    int*  off  = tmp  + 50048;                       // 50,056 (N+1 used)
    int*  nbr  = off  + 50056;                       // 800,000
    int*  goff = nbr  + 800000;                      // 320 (257 used)
    float* B   = (float*)(goff + 320);               // 3,200,000
    float* H1  = B   + NF;                           // 3,200,000
    float* H2  = H1  + NF;                           // 3,200,000
    float* cb  = H2  + NF;                           // 16,384
    float* m1  = cb  + NUM_GRAPHS * HD;              // 65,536
    float* m2  = m1  + NUM_GRAPHS * 256;             // 32,768
    float* m3  = m2  + NUM_GRAPHS * 128;             // 16,384
    float* endp= m3  + NUM_GRAPHS * 64;

    const size_t NEED = (size_t)((char*)endp - wsb);
    if (ws_size < NEED) {
        k_diag<<<(out_size + 255) / 256, 256, 0, stream>>>((float*)d_out, out_size,
                                                           (float)(ws_size >> 20));
        return;
    }

    const int TB = 256;
    const int gNE = (N_EDGES + TB - 1) / TB;
    const int gNF = (int)((NF + TB - 1) / TB);        // 12500
    const int gXW = (N_NODES / 8 * 64 + TB - 1) / TB; // 1563

    hipMemsetAsync(cnti, 0, 2 * 50048 * sizeof(int), stream);   // cnti + tmp

    // ---- CSR build (reused by all 3 layers) ----
    k_count<<<gNE, TB, 0, stream>>>(dstp, cnti);
    k_scan<<<1, 1024, 0, stream>>>(cnti, off);
    k_fill<<<gNE, TB, 0, stream>>>(srcp, dstp, off, tmp, nbr);

    k_gbounds<<<1, 512, 0, stream>>>(batch, goff);

    // ---- SAGE layer 1: x(128) -> H1 ----
    k_xform2<IN_DIM><<<gXW, TB, 0, stream>>>(x, W1l, W1r, b1l, B, H1);
    k_gather<<<gNF, TB, 0, stream>>>(off, nbr, B, H1);

    // ---- SAGE layer 2: H1 -> H2 ----
    k_xform2<HD><<<gXW, TB, 0, stream>>>(H1, W2l, W2r, b2l, B, H2);
    k_gather<<<gNF, TB, 0, stream>>>(off, nbr, B, H2);

    // ---- SAGE layer 3: H2 -> H1 ----
    k_xform2<HD><<<gXW, TB, 0, stream>>>(H2, W3l, W3r, b3l, B, H1);
    k_gather<<<gNF, TB, 0, stream>>>(off, nbr, B, H1);

    // ---- global mean pool ----
    k_pool2<<<NUM_GRAPHS, TB, 0, stream>>>(goff, H1, cb);

    // ---- MLP head ----
    k_head_gemm3<256><<<64, TB, 0, stream>>>(cb, lin1_w, lin1_b, m1, 64);
    k_bn_tanh3<<<4, TB, 0, stream>>>(m1, g1, be1, 256);
    k_head_gemm3<128><<<32, TB, 0, stream>>>(m1, lin2_w, lin2_b, m2, 256);
    k_bn_tanh3<<<2, TB, 0, stream>>>(m2, g2, be2, 128);
    k_head_gemm3<64><<<16, TB, 0, stream>>>(m2, lin3_w, lin3_b, m3, 128);
    k_bn_tanh3<<<1, TB, 0, stream>>>(m3, g3, be3, 64);
    k_final<<<(NUM_GRAPHS * 10 + TB - 1) / TB, TB, 0, stream>>>(m3, lin4_w, lin4_b, (float*)d_out);
}

// Round 11
// 609.342 us; speedup vs baseline: 2.1428x; 1.0908x over previous
//
#include <hip/hip_runtime.h>
#include <hip/hip_bf16.h>

#define N_NODES   50000
#define N_EDGES   800000
#define NUM_GRAPHS 256
#define IN_DIM    128
#define HD        64
#define EPS       1e-5f

// ---------------- diagnostics ----------------
__global__ void k_diag(float* __restrict__ out, int n, float v) {
    int t = blockIdx.x * 256 + threadIdx.x;
    if (t < n) out[t] = v;
}

// ---------------- CSR build ----------------
__global__ void k_count(const int* __restrict__ dst, int* __restrict__ cnti) {
    int e = blockIdx.x * 256 + threadIdx.x;
    if (e < N_EDGES) atomicAdd(&cnti[dst[e]], 1);
}

// single block, 1024 threads: exclusive prefix sum of cnti -> off[0..N_NODES]
__global__ void k_scan(const int* __restrict__ cnti, int* __restrict__ off) {
    __shared__ int wsum[16];
    __shared__ int base;
    int lane = threadIdx.x & 63, wid = threadIdx.x >> 6;
    if (threadIdx.x == 0) base = 0;
    __syncthreads();
    for (int c = 0; c < N_NODES; c += 1024) {
        int idx = c + threadIdx.x;
        int v = (idx < N_NODES) ? cnti[idx] : 0;
        int s = v;
        #pragma unroll
        for (int o = 1; o < 64; o <<= 1) {
            int u = __shfl_up(s, o);
            if (lane >= o) s += u;
        }
        if (lane == 63) wsum[wid] = s;
        __syncthreads();
        if (wid == 0 && lane < 16) {
            int w = wsum[lane];
            #pragma unroll
            for (int o = 1; o < 16; o <<= 1) {
                int u = __shfl_up(w, o);
                if (lane >= o) w += u;
            }
            wsum[lane] = w;
        }
        __syncthreads();
        int wbase = (wid > 0) ? wsum[wid - 1] : 0;
        int total = wsum[15];
        if (idx < N_NODES) off[idx] = base + wbase + s - v;
        __syncthreads();
        if (threadIdx.x == 0) base += total;
        __syncthreads();
    }
    if (threadIdx.x == 0) off[N_NODES] = base;
}

__global__ void k_fill(const int* __restrict__ src, const int* __restrict__ dst,
                       const int* __restrict__ off, int* __restrict__ tmp,
                       int* __restrict__ nbr) {
    int e = blockIdx.x * 256 + threadIdx.x;
    if (e >= N_EDGES) return;
    int d = dst[e];
    int p = atomicAdd(&tmp[d], 1);
    nbr[off[d] + p] = src[e];
}

// ---- graph boundaries in sorted batch ----
__global__ void k_gbounds(const int* __restrict__ batch, int* __restrict__ goff) {
    int g = blockIdx.x * blockDim.x + threadIdx.x;
    if (g > NUM_GRAPHS) return;
    int lo = 0, hi = N_NODES;
    while (lo < hi) {
        int mid = (lo + hi) >> 1;
        if (batch[mid] < g) lo = mid + 1; else hi = mid;
    }
    goff[g] = lo;
}

// ---- fused transform, LDS-staged X tile: B = X@Wl ; C = X@Wr + bl ----
// block = 256 thr (4 waves), 32 nodes/block; wave handles 8 nodes, lane = col.
template <int K>
__global__ __launch_bounds__(256) void k_xform3(
        const float* __restrict__ X, const float* __restrict__ Wl,
        const float* __restrict__ Wr, const float* __restrict__ bl,
        float* __restrict__ B, float* __restrict__ C) {
    __shared__ float tile[32 * K];
    const int NPW = 8;
    int nodes0 = blockIdx.x * 32;
    // ---- cooperative coalesced staging (float4) ----
    {
        const int total4 = 32 * K / 4;              // float4 count
        int nmax4 = (N_NODES - nodes0) * K / 4;     // valid float4s (node-major rows)
        const float4* Xg = (const float4*)(X + (long)nodes0 * K);
        float4* tg = (float4*)tile;
        for (int idx = threadIdx.x; idx < total4; idx += 256) {
            float4 v = make_float4(0.f, 0.f, 0.f, 0.f);
            if (idx < nmax4) v = Xg[idx];
            tg[idx] = v;
        }
    }
    __syncthreads();
    int wave = threadIdx.x >> 6, j = threadIdx.x & 63;
    long base = (long)nodes0 + wave * NPW;
    if (base >= N_NODES) return;
    float accB[NPW], accC[NPW];
    #pragma unroll
    for (int n = 0; n < NPW; n++) { accB[n] = 0.f; accC[n] = 0.f; }
    const float* Xs = tile + (wave * NPW) * K;
    for (int kc = 0; kc < K; kc += 4) {
        float wl0 = Wl[(kc + 0) * HD + j], wr0 = Wr[(kc + 0) * HD + j];
        float wl1 = Wl[(kc + 1) * HD + j], wr1 = Wr[(kc + 1) * HD + j];
        float wl2 = Wl[(kc + 2) * HD + j], wr2 = Wr[(kc + 2) * HD + j];
        float wl3 = Wl[(kc + 3) * HD + j], wr3 = Wr[(kc + 3) * HD + j];
        #pragma unroll
        for (int n = 0; n < NPW; n++) {
            float4 xv = *(const float4*)(Xs + n * K + kc);
            accB[n] = fmaf(xv.x, wl0, accB[n]);
            accC[n] = fmaf(xv.x, wr0, accC[n]);
            accB[n] = fmaf(xv.y, wl1, accB[n]);
            accC[n] = fmaf(xv.y, wr1, accC[n]);
            accB[n] = fmaf(xv.z, wl2, accB[n]);
            accC[n] = fmaf(xv.z, wr2, accC[n]);
            accB[n] = fmaf(xv.w, wl3, accB[n]);
            accC[n] = fmaf(xv.w, wr3, accC[n]);
        }
    }
    float bb = bl[j];
    int nact = (int)min((long)NPW, (long)N_NODES - base);
    for (int n = 0; n < nact; n++) {
        long i = base + n;
        B[i * HD + j] = accB[n];
        C[i * HD + j] = accC[n] + bb;
    }
}

// ---- CSR gather: C[i,:] += mean_{s in nbr(i)} B[s,:]  (one wave per node) ----
__global__ void k_gather(const int* __restrict__ off, const int* __restrict__ nbr,
                         const float* __restrict__ B, float* __restrict__ C) {
    int t = blockIdx.x * 256 + threadIdx.x;
    int i = t >> 6, j = t & 63;
    if (i >= N_NODES) return;
    int beg = off[i], end = off[i + 1];
    float s0 = 0.f, s1 = 0.f, s2 = 0.f, s3 = 0.f;
    float s4 = 0.f, s5 = 0.f, s6 = 0.f, s7 = 0.f;
    for (int base = beg; base < end; base += 64) {
        int idx = base + j;
        int nv = (idx < end) ? nbr[idx] : 0;
        int m = min(64, end - base);
        int tt = 0;
        for (; tt + 8 <= m; tt += 8) {
            int n0 = __shfl(nv, tt + 0);
            int n1 = __shfl(nv, tt + 1);
            int n2 = __shfl(nv, tt + 2);
            int n3 = __shfl(nv, tt + 3);
            int n4 = __shfl(nv, tt + 4);
            int n5 = __shfl(nv, tt + 5);
            int n6 = __shfl(nv, tt + 6);
            int n7 = __shfl(nv, tt + 7);
            s0 += B[(long)n0 * HD + j];
            s1 += B[(long)n1 * HD + j];
            s2 += B[(long)n2 * HD + j];
            s3 += B[(long)n3 * HD + j];
            s4 += B[(long)n4 * HD + j];
            s5 += B[(long)n5 * HD + j];
            s6 += B[(long)n6 * HD + j];
            s7 += B[(long)n7 * HD + j];
        }
        for (; tt < m; ++tt) {
            int nb = __shfl(nv, tt);
            s0 += B[(long)nb * HD + j];
        }
    }
    int deg = end - beg;
    float inv = 1.0f / (float)max(deg, 1);
    C[(long)i * HD + j] += ((s0 + s1) + (s2 + s3) + ((s4 + s5) + (s6 + s7))) * inv;
}

// ---- global mean pool via sorted-batch segments ----
__global__ void k_pool2(const int* __restrict__ goff, const float* __restrict__ h,
                        float* __restrict__ cb) {
    __shared__ float red[4][64];
    int g = blockIdx.x;
    int j = threadIdx.x & 63, r = threadIdx.x >> 6;
    int beg = goff[g], end = goff[g + 1];
    float s = 0.f;
    for (int n = beg + r; n < end; n += 4) s += h[(long)n * HD + j];
    red[r][j] = s;
    __syncthreads();
    if (r == 0) {
        float tot = (red[0][j] + red[1][j]) + (red[2][j] + red[3][j]);
        int cnt = end - beg;
        cb[g * HD + j] = tot / (float)max(cnt, 1);
    }
}

// ---- head GEMM: thread = 4 rows x 1 col, K unrolled x4, float4 A loads ----
template <int NN>
__global__ void k_head_gemm3(const float* __restrict__ A, const float* __restrict__ W,
                             const float* __restrict__ b, float* __restrict__ out,
                             int K) {
    int t = blockIdx.x * 256 + threadIdx.x;
    int j = t % NN;
    int r0 = (t / NN) * 4;
    float s0, s1, s2, s3;
    s0 = s1 = s2 = s3 = b[j];
    for (int k = 0; k < K; k += 4) {
        float w0 = W[(k + 0) * NN + j];
        float w1 = W[(k + 1) * NN + j];
        float w2 = W[(k + 2) * NN + j];
        float w3 = W[(k + 3) * NN + j];
        float4 a0 = *(const float4*)(A + (r0 + 0) * K + k);
        float4 a1 = *(const float4*)(A + (r0 + 1) * K + k);
        float4 a2 = *(const float4*)(A + (r0 + 2) * K + k);
        float4 a3 = *(const float4*)(A + (r0 + 3) * K + k);
        s0 = fmaf(a0.x, w0, s0); s0 = fmaf(a0.y, w1, s0); s0 = fmaf(a0.z, w2, s0); s0 = fmaf(a0.w, w3, s0);
        s1 = fmaf(a1.x, w0, s1); s1 = fmaf(a1.y, w1, s1); s1 = fmaf(a1.z, w2, s1); s1 = fmaf(a1.w, w3, s1);
        s2 = fmaf(a2.x, w0, s2); s2 = fmaf(a2.y, w1, s2); s2 = fmaf(a2.z, w2, s2); s2 = fmaf(a2.w, w3, s2);
        s3 = fmaf(a3.x, w0, s3); s3 = fmaf(a3.y, w1, s3); s3 = fmaf(a3.z, w2, s3); s3 = fmaf(a3.w, w3, s3);
    }
    out[(r0 + 0) * NN + j] = s0;
    out[(r0 + 1) * NN + j] = s1;
    out[(r0 + 2) * NN + j] = s2;
    out[(r0 + 3) * NN + j] = s3;
}

// ---- BN(train-stats)+tanh: block = 4 row-lanes x 64 cols, coalesced ----
__global__ void k_bn_tanh3(float* __restrict__ X, const float* __restrict__ g,
                           const float* __restrict__ be, int N) {
    __shared__ float ssum[4][64], ssq[4][64], sscale[64], smean[64];
    int j = blockIdx.x * 64 + (threadIdx.x & 63);
    int jj = threadIdx.x & 63, rl = threadIdx.x >> 6;
    float sum = 0.f, sq = 0.f;
    for (int r = rl; r < NUM_GRAPHS; r += 4) {
        float v = X[r * N + j];
        sum += v; sq += v * v;
    }
    ssum[rl][jj] = sum; ssq[rl][jj] = sq;
    __syncthreads();
    if (rl == 0) {
        float S = (ssum[0][jj] + ssum[1][jj]) + (ssum[2][jj] + ssum[3][jj]);
        float Q = (ssq[0][jj] + ssq[1][jj]) + (ssq[2][jj] + ssq[3][jj]);
        float mean = S * (1.0f / NUM_GRAPHS);
        float var = Q * (1.0f / NUM_GRAPHS) - mean * mean;
        smean[jj] = mean;
        sscale[jj] = rsqrtf(fmaxf(var, 0.f) + EPS) * g[j];
    }
    __syncthreads();
    float mean = smean[jj], scale = sscale[jj], sh = be[j];
    for (int r = rl; r < NUM_GRAPHS; r += 4) {
        float v = X[r * N + j];
        X[r * N + j] = tanhf((v - mean) * scale + sh);
    }
}

// final: out = A(256x64) @ W(64x10) + b
__global__ void k_final(const float* __restrict__ A, const float* __restrict__ W,
                        const float* __restrict__ b, float* __restrict__ out) {
    int t = blockIdx.x * 256 + threadIdx.x;
    if (t >= NUM_GRAPHS * 10) return;
    int i = t / 10, j = t % 10;
    float s = b[j];
    #pragma unroll
    for (int k = 0; k < 64; k++) s += A[i * 64 + k] * W[k * 10 + j];
    out[t] = s;
}

extern "C" void kernel_launch(void* const* d_in, const int* in_sizes, int n_in,
                              void* d_out, int out_size, void* d_ws, size_t ws_size,
                              hipStream_t stream) {
    const float* x     = (const float*)d_in[0];
    const int*   ei    = (const int*) d_in[1];
    const int*   batch = (const int*) d_in[2];
    const float *W1l = (const float*)d_in[3],  *b1l = (const float*)d_in[4],  *W1r = (const float*)d_in[5];
    const float *W2l = (const float*)d_in[6],  *b2l = (const float*)d_in[7],  *W2r = (const float*)d_in[8];
    const float *W3l = (const float*)d_in[9],  *b3l = (const float*)d_in[10], *W3r = (const float*)d_in[11];
    const float *lin1_w = (const float*)d_in[12], *lin1_b = (const float*)d_in[13];
    const float *g1 = (const float*)d_in[14], *be1 = (const float*)d_in[15];
    const float *lin2_w = (const float*)d_in[16], *lin2_b = (const float*)d_in[17];
    const float *g2 = (const float*)d_in[18], *be2 = (const float*)d_in[19];
    const float *lin3_w = (const float*)d_in[20], *lin3_b = (const float*)d_in[21];
    const float *g3 = (const float*)d_in[22], *be3 = (const float*)d_in[23];
    const float *lin4_w = (const float*)d_in[24], *lin4_b = (const float*)d_in[25];

    const int* srcp = ei;
    const int* dstp = ei + N_EDGES;

    // ---- workspace layout ----
    const long NF = (long)N_NODES * HD;              // 3,200,000
    char* wsb  = (char*)d_ws;
    int*  cnti = (int*)wsb;                          // 50,048
    int*  tmp  = cnti + 50048;                       // 50,048
    int*  off  = tmp  + 50048;                       // 50,056 (N+1 used)
    int*  nbr  = off  + 50056;                       // 800,000
    int*  goff = nbr  + 800000;                      // 320 (257 used)
    float* B   = (float*)(goff + 320);               // 3,200,000
    float* H1  = B   + NF;                           // 3,200,000
    float* H2  = H1  + NF;                           // 3,200,000
    float* cb  = H2  + NF;                           // 16,384
    float* m1  = cb  + NUM_GRAPHS * HD;              // 65,536
    float* m2  = m1  + NUM_GRAPHS * 256;             // 32,768
    float* m3  = m2  + NUM_GRAPHS * 128;             // 16,384
    float* endp= m3  + NUM_GRAPHS * 64;

    const size_t NEED = (size_t)((char*)endp - wsb);
    if (ws_size < NEED) {
        k_diag<<<(out_size + 255) / 256, 256, 0, stream>>>((float*)d_out, out_size,
                                                           (float)(ws_size >> 20));
        return;
    }

    const int TB = 256;
    const int gNE = (N_EDGES + TB - 1) / TB;
    const int gNF = (int)((NF + TB - 1) / TB);        // 12500
    const int gXB = (N_NODES + 31) / 32;              // 1563 blocks (32 nodes each)

    hipMemsetAsync(cnti, 0, 2 * 50048 * sizeof(int), stream);   // cnti + tmp

    // ---- CSR build (reused by all 3 layers) ----
    k_count<<<gNE, TB, 0, stream>>>(dstp, cnti);
    k_scan<<<1, 1024, 0, stream>>>(cnti, off);
    k_fill<<<gNE, TB, 0, stream>>>(srcp, dstp, off, tmp, nbr);

    k_gbounds<<<1, 512, 0, stream>>>(batch, goff);

    // ---- SAGE layer 1: x(128) -> H1 ----
    k_xform3<IN_DIM><<<gXB, TB, 0, stream>>>(x, W1l, W1r, b1l, B, H1);
    k_gather<<<gNF, TB, 0, stream>>>(off, nbr, B, H1);

    // ---- SAGE layer 2: H1 -> H2 ----
    k_xform3<HD><<<gXB, TB, 0, stream>>>(H1, W2l, W2r, b2l, B, H2);
    k_gather<<<gNF, TB, 0, stream>>>(off, nbr, B, H2);

    // ---- SAGE layer 3: H2 -> H1 ----
    k_xform3<HD><<<gXB, TB, 0, stream>>>(H2, W3l, W3r, b3l, B, H1);
    k_gather<<<gNF, TB, 0, stream>>>(off, nbr, B, H1);

    // ---- global mean pool ----
    k_pool2<<<NUM_GRAPHS, TB, 0, stream>>>(goff, H1, cb);

    // ---- MLP head ----
    k_head_gemm3<256><<<64, TB, 0, stream>>>(cb, lin1_w, lin1_b, m1, 64);
    k_bn_tanh3<<<4, TB, 0, stream>>>(m1, g1, be1, 256);
    k_head_gemm3<128><<<32, TB, 0, stream>>>(m1, lin2_w, lin2_b, m2, 256);
    k_bn_tanh3<<<2, TB, 0, stream>>>(m2, g2, be2, 128);
    k_head_gemm3<64><<<16, TB, 0, stream>>>(m2, lin3_w, lin3_b, m3, 128);
    k_bn_tanh3<<<1, TB, 0, stream>>>(m3, g3, be3, 64);
    k_final<<<(NUM_GRAPHS * 10 + TB - 1) / TB, TB, 0, stream>>>(m3, lin4_w, lin4_b, (float*)d_out);
}

// Round 12
// 570.073 us; speedup vs baseline: 2.2905x; 1.0689x over previous
//
#include <hip/hip_runtime.h>
#include <hip/hip_bf16.h>

#define N_NODES   50000
#define N_EDGES   800000
#define NUM_GRAPHS 256
#define IN_DIM    128
#define HD        64
#define EPS       1e-5f
#define SCAN_NB   196      // ceil(50000/256)

// ---------------- diagnostics ----------------
__global__ void k_diag(float* __restrict__ out, int n, float v) {
    int t = blockIdx.x * 256 + threadIdx.x;
    if (t < n) out[t] = v;
}

// ---------------- CSR build ----------------
__global__ void k_count(const int* __restrict__ dst, int* __restrict__ cnti) {
    int e = blockIdx.x * 256 + threadIdx.x;
    if (e < N_EDGES) atomicAdd(&cnti[dst[e]], 1);
}

// phase 1: block-local exclusive scan (256/block) + block totals
__global__ void k_scan1(const int* __restrict__ cnti, int* __restrict__ off,
                        int* __restrict__ bsum) {
    __shared__ int wsum[4];
    int idx = blockIdx.x * 256 + threadIdx.x;
    int lane = threadIdx.x & 63, wid = threadIdx.x >> 6;
    int v = (idx < N_NODES) ? cnti[idx] : 0;
    int s = v;
    #pragma unroll
    for (int o = 1; o < 64; o <<= 1) {
        int u = __shfl_up(s, o);
        if (lane >= o) s += u;
    }
    if (lane == 63) wsum[wid] = s;
    __syncthreads();
    int wbase = 0;
    #pragma unroll
    for (int w = 0; w < 4; w++) wbase += (w < wid) ? wsum[w] : 0;
    if (idx < N_NODES) off[idx] = wbase + s - v;   // block-local exclusive
    if (threadIdx.x == 255) bsum[blockIdx.x] = wbase + s;
}

// phase 2: single block scans the SCAN_NB block totals (exclusive)
__global__ void k_scan2(const int* __restrict__ bsum, int* __restrict__ boff) {
    __shared__ int wsum[4];
    int lane = threadIdx.x & 63, wid = threadIdx.x >> 6;
    int v = (threadIdx.x < SCAN_NB) ? bsum[threadIdx.x] : 0;
    int s = v;
    #pragma unroll
    for (int o = 1; o < 64; o <<= 1) {
        int u = __shfl_up(s, o);
        if (lane >= o) s += u;
    }
    if (lane == 63) wsum[wid] = s;
    __syncthreads();
    int wbase = 0;
    #pragma unroll
    for (int w = 0; w < 4; w++) wbase += (w < wid) ? wsum[w] : 0;
    if (threadIdx.x < SCAN_NB) boff[threadIdx.x] = wbase + s - v;
}

// phase 3: add block offsets; set off[N_NODES] = N_EDGES
__global__ void k_scan3(int* __restrict__ off, const int* __restrict__ boff) {
    int idx = blockIdx.x * 256 + threadIdx.x;
    if (idx < N_NODES) off[idx] += boff[blockIdx.x];
    else if (idx == N_NODES) off[N_NODES] = N_EDGES;
}

__global__ void k_fill(const int* __restrict__ src, const int* __restrict__ dst,
                       const int* __restrict__ off, int* __restrict__ tmp,
                       int* __restrict__ nbr) {
    int e = blockIdx.x * 256 + threadIdx.x;
    if (e >= N_EDGES) return;
    int d = dst[e];
    int p = atomicAdd(&tmp[d], 1);
    nbr[off[d] + p] = src[e];
}

// ---- graph boundaries in sorted batch ----
__global__ void k_gbounds(const int* __restrict__ batch, int* __restrict__ goff) {
    int g = blockIdx.x * blockDim.x + threadIdx.x;
    if (g > NUM_GRAPHS) return;
    int lo = 0, hi = N_NODES;
    while (lo < hi) {
        int mid = (lo + hi) >> 1;
        if (batch[mid] < g) lo = mid + 1; else hi = mid;
    }
    goff[g] = lo;
}

// ---- fused transform, LDS-staged X tile: B = X@Wl ; C = X@Wr + bl ----
template <int K>
__global__ __launch_bounds__(256) void k_xform3(
        const float* __restrict__ X, const float* __restrict__ Wl,
        const float* __restrict__ Wr, const float* __restrict__ bl,
        float* __restrict__ B, float* __restrict__ C) {
    __shared__ float tile[32 * K];
    const int NPW = 8;
    int nodes0 = blockIdx.x * 32;
    {
        const int total4 = 32 * K / 4;
        int nmax4 = (N_NODES - nodes0) * K / 4;
        const float4* Xg = (const float4*)(X + (long)nodes0 * K);
        float4* tg = (float4*)tile;
        for (int idx = threadIdx.x; idx < total4; idx += 256) {
            float4 v = make_float4(0.f, 0.f, 0.f, 0.f);
            if (idx < nmax4) v = Xg[idx];
            tg[idx] = v;
        }
    }
    __syncthreads();
    int wave = threadIdx.x >> 6, j = threadIdx.x & 63;
    long base = (long)nodes0 + wave * NPW;
    if (base >= N_NODES) return;
    float accB[NPW], accC[NPW];
    #pragma unroll
    for (int n = 0; n < NPW; n++) { accB[n] = 0.f; accC[n] = 0.f; }
    const float* Xs = tile + (wave * NPW) * K;
    for (int kc = 0; kc < K; kc += 4) {
        float wl0 = Wl[(kc + 0) * HD + j], wr0 = Wr[(kc + 0) * HD + j];
        float wl1 = Wl[(kc + 1) * HD + j], wr1 = Wr[(kc + 1) * HD + j];
        float wl2 = Wl[(kc + 2) * HD + j], wr2 = Wr[(kc + 2) * HD + j];
        float wl3 = Wl[(kc + 3) * HD + j], wr3 = Wr[(kc + 3) * HD + j];
        #pragma unroll
        for (int n = 0; n < NPW; n++) {
            float4 xv = *(const float4*)(Xs + n * K + kc);
            accB[n] = fmaf(xv.x, wl0, accB[n]);
            accC[n] = fmaf(xv.x, wr0, accC[n]);
            accB[n] = fmaf(xv.y, wl1, accB[n]);
            accC[n] = fmaf(xv.y, wr1, accC[n]);
            accB[n] = fmaf(xv.z, wl2, accB[n]);
            accC[n] = fmaf(xv.z, wr2, accC[n]);
            accB[n] = fmaf(xv.w, wl3, accB[n]);
            accC[n] = fmaf(xv.w, wr3, accC[n]);
        }
    }
    float bb = bl[j];
    int nact = (int)min((long)NPW, (long)N_NODES - base);
    for (int n = 0; n < nact; n++) {
        long i = base + n;
        B[i * HD + j] = accB[n];
        C[i * HD + j] = accC[n] + bb;
    }
}

// ---- CSR gather: C[i,:] += mean_{s in nbr(i)} B[s,:]  (one wave per node) ----
__global__ void k_gather(const int* __restrict__ off, const int* __restrict__ nbr,
                         const float* __restrict__ B, float* __restrict__ C) {
    int t = blockIdx.x * 256 + threadIdx.x;
    int i = t >> 6, j = t & 63;
    if (i >= N_NODES) return;
    int beg = off[i], end = off[i + 1];
    float s0 = 0.f, s1 = 0.f, s2 = 0.f, s3 = 0.f;
    float s4 = 0.f, s5 = 0.f, s6 = 0.f, s7 = 0.f;
    for (int base = beg; base < end; base += 64) {
        int idx = base + j;
        int nv = (idx < end) ? nbr[idx] : 0;
        int m = min(64, end - base);
        int tt = 0;
        for (; tt + 8 <= m; tt += 8) {
            int n0 = __shfl(nv, tt + 0);
            int n1 = __shfl(nv, tt + 1);
            int n2 = __shfl(nv, tt + 2);
            int n3 = __shfl(nv, tt + 3);
            int n4 = __shfl(nv, tt + 4);
            int n5 = __shfl(nv, tt + 5);
            int n6 = __shfl(nv, tt + 6);
            int n7 = __shfl(nv, tt + 7);
            s0 += B[(long)n0 * HD + j];
            s1 += B[(long)n1 * HD + j];
            s2 += B[(long)n2 * HD + j];
            s3 += B[(long)n3 * HD + j];
            s4 += B[(long)n4 * HD + j];
            s5 += B[(long)n5 * HD + j];
            s6 += B[(long)n6 * HD + j];
            s7 += B[(long)n7 * HD + j];
        }
        for (; tt < m; ++tt) {
            int nb = __shfl(nv, tt);
            s0 += B[(long)nb * HD + j];
        }
    }
    int deg = end - beg;
    float inv = 1.0f / (float)max(deg, 1);
    C[(long)i * HD + j] += ((s0 + s1) + (s2 + s3) + ((s4 + s5) + (s6 + s7))) * inv;
}

// ---- global mean pool via sorted-batch segments ----
__global__ void k_pool2(const int* __restrict__ goff, const float* __restrict__ h,
                        float* __restrict__ cb) {
    __shared__ float red[4][64];
    int g = blockIdx.x;
    int j = threadIdx.x & 63, r = threadIdx.x >> 6;
    int beg = goff[g], end = goff[g + 1];
    float s = 0.f;
    for (int n = beg + r; n < end; n += 4) s += h[(long)n * HD + j];
    red[r][j] = s;
    __syncthreads();
    if (r == 0) {
        float tot = (red[0][j] + red[1][j]) + (red[2][j] + red[3][j]);
        int cnt = end - beg;
        cb[g * HD + j] = tot / (float)max(cnt, 1);
    }
}

// ---- head GEMM: thread = 4 rows x 1 col, K unrolled x4, float4 A loads ----
template <int NN>
__global__ void k_head_gemm3(const float* __restrict__ A, const float* __restrict__ W,
                             const float* __restrict__ b, float* __restrict__ out,
                             int K) {
    int t = blockIdx.x * 256 + threadIdx.x;
    int j = t % NN;
    int r0 = (t / NN) * 4;
    float s0, s1, s2, s3;
    s0 = s1 = s2 = s3 = b[j];
    for (int k = 0; k < K; k += 4) {
        float w0 = W[(k + 0) * NN + j];
        float w1 = W[(k + 1) * NN + j];
        float w2 = W[(k + 2) * NN + j];
        float w3 = W[(k + 3) * NN + j];
        float4 a0 = *(const float4*)(A + (r0 + 0) * K + k);
        float4 a1 = *(const float4*)(A + (r0 + 1) * K + k);
        float4 a2 = *(const float4*)(A + (r0 + 2) * K + k);
        float4 a3 = *(const float4*)(A + (r0 + 3) * K + k);
        s0 = fmaf(a0.x, w0, s0); s0 = fmaf(a0.y, w1, s0); s0 = fmaf(a0.z, w2, s0); s0 = fmaf(a0.w, w3, s0);
        s1 = fmaf(a1.x, w0, s1); s1 = fmaf(a1.y, w1, s1); s1 = fmaf(a1.z, w2, s1); s1 = fmaf(a1.w, w3, s1);
        s2 = fmaf(a2.x, w0, s2); s2 = fmaf(a2.y, w1, s2); s2 = fmaf(a2.z, w2, s2); s2 = fmaf(a2.w, w3, s2);
        s3 = fmaf(a3.x, w0, s3); s3 = fmaf(a3.y, w1, s3); s3 = fmaf(a3.z, w2, s3); s3 = fmaf(a3.w, w3, s3);
    }
    out[(r0 + 0) * NN + j] = s0;
    out[(r0 + 1) * NN + j] = s1;
    out[(r0 + 2) * NN + j] = s2;
    out[(r0 + 3) * NN + j] = s3;
}

// ---- BN(train-stats)+tanh: block = 4 row-lanes x 64 cols, coalesced ----
__global__ void k_bn_tanh3(float* __restrict__ X, const float* __restrict__ g,
                           const float* __restrict__ be, int N) {
    __shared__ float ssum[4][64], ssq[4][64], sscale[64], smean[64];
    int j = blockIdx.x * 64 + (threadIdx.x & 63);
    int jj = threadIdx.x & 63, rl = threadIdx.x >> 6;
    float sum = 0.f, sq = 0.f;
    for (int r = rl; r < NUM_GRAPHS; r += 4) {
        float v = X[r * N + j];
        sum += v; sq += v * v;
    }
    ssum[rl][jj] = sum; ssq[rl][jj] = sq;
    __syncthreads();
    if (rl == 0) {
        float S = (ssum[0][jj] + ssum[1][jj]) + (ssum[2][jj] + ssum[3][jj]);
        float Q = (ssq[0][jj] + ssq[1][jj]) + (ssq[2][jj] + ssq[3][jj]);
        float mean = S * (1.0f / NUM_GRAPHS);
        float var = Q * (1.0f / NUM_GRAPHS) - mean * mean;
        smean[jj] = mean;
        sscale[jj] = rsqrtf(fmaxf(var, 0.f) + EPS) * g[j];
    }
    __syncthreads();
    float mean = smean[jj], scale = sscale[jj], sh = be[j];
    for (int r = rl; r < NUM_GRAPHS; r += 4) {
        float v = X[r * N + j];
        X[r * N + j] = tanhf((v - mean) * scale + sh);
    }
}

// final: out = A(256x64) @ W(64x10) + b
__global__ void k_final(const float* __restrict__ A, const float* __restrict__ W,
                        const float* __restrict__ b, float* __restrict__ out) {
    int t = blockIdx.x * 256 + threadIdx.x;
    if (t >= NUM_GRAPHS * 10) return;
    int i = t / 10, j = t % 10;
    float s = b[j];
    #pragma unroll
    for (int k = 0; k < 64; k++) s += A[i * 64 + k] * W[k * 10 + j];
    out[t] = s;
}

extern "C" void kernel_launch(void* const* d_in, const int* in_sizes, int n_in,
                              void* d_out, int out_size, void* d_ws, size_t ws_size,
                              hipStream_t stream) {
    const float* x     = (const float*)d_in[0];
    const int*   ei    = (const int*) d_in[1];
    const int*   batch = (const int*) d_in[2];
    const float *W1l = (const float*)d_in[3],  *b1l = (const float*)d_in[4],  *W1r = (const float*)d_in[5];
    const float *W2l = (const float*)d_in[6],  *b2l = (const float*)d_in[7],  *W2r = (const float*)d_in[8];
    const float *W3l = (const float*)d_in[9],  *b3l = (const float*)d_in[10], *W3r = (const float*)d_in[11];
    const float *lin1_w = (const float*)d_in[12], *lin1_b = (const float*)d_in[13];
    const float *g1 = (const float*)d_in[14], *be1 = (const float*)d_in[15];
    const float *lin2_w = (const float*)d_in[16], *lin2_b = (const float*)d_in[17];
    const float *g2 = (const float*)d_in[18], *be2 = (const float*)d_in[19];
    const float *lin3_w = (const float*)d_in[20], *lin3_b = (const float*)d_in[21];
    const float *g3 = (const float*)d_in[22], *be3 = (const float*)d_in[23];
    const float *lin4_w = (const float*)d_in[24], *lin4_b = (const float*)d_in[25];

    const int* srcp = ei;
    const int* dstp = ei + N_EDGES;

    // ---- workspace layout ----
    const long NF = (long)N_NODES * HD;              // 3,200,000
    char* wsb  = (char*)d_ws;
    int*  cnti = (int*)wsb;                          // 50,048
    int*  tmp  = cnti + 50048;                       // 50,048
    int*  off  = tmp  + 50048;                       // 50,056 (N+1 used)
    int*  nbr  = off  + 50056;                       // 800,000
    int*  goff = nbr  + 800000;                      // 320 (257 used)
    int*  bsum = goff + 320;                         // 256
    int*  boff = bsum + 256;                         // 256
    float* B   = (float*)(boff + 256);               // 3,200,000
    float* H1  = B   + NF;                           // 3,200,000
    float* H2  = H1  + NF;                           // 3,200,000
    float* cb  = H2  + NF;                           // 16,384
    float* m1  = cb  + NUM_GRAPHS * HD;              // 65,536
    float* m2  = m1  + NUM_GRAPHS * 256;             // 32,768
    float* m3  = m2  + NUM_GRAPHS * 128;             // 16,384
    float* endp= m3  + NUM_GRAPHS * 64;

    const size_t NEED = (size_t)((char*)endp - wsb);
    if (ws_size < NEED) {
        k_diag<<<(out_size + 255) / 256, 256, 0, stream>>>((float*)d_out, out_size,
                                                           (float)(ws_size >> 20));
        return;
    }

    const int TB = 256;
    const int gNE = (N_EDGES + TB - 1) / TB;
    const int gNF = (int)((NF + TB - 1) / TB);        // 12500
    const int gXB = (N_NODES + 31) / 32;              // 1563 blocks (32 nodes each)

    hipMemsetAsync(cnti, 0, 2 * 50048 * sizeof(int), stream);   // cnti + tmp

    // ---- CSR build: count + 3-phase hierarchical scan + fill ----
    k_count<<<gNE, TB, 0, stream>>>(dstp, cnti);
    k_scan1<<<SCAN_NB, TB, 0, stream>>>(cnti, off, bsum);
    k_scan2<<<1, TB, 0, stream>>>(bsum, boff);
    k_scan3<<<SCAN_NB, TB, 0, stream>>>(off, boff);
    k_fill<<<gNE, TB, 0, stream>>>(srcp, dstp, off, tmp, nbr);

    k_gbounds<<<1, 512, 0, stream>>>(batch, goff);

    // ---- SAGE layer 1: x(128) -> H1 ----
    k_xform3<IN_DIM><<<gXB, TB, 0, stream>>>(x, W1l, W1r, b1l, B, H1);
    k_gather<<<gNF, TB, 0, stream>>>(off, nbr, B, H1);

    // ---- SAGE layer 2: H1 -> H2 ----
    k_xform3<HD><<<gXB, TB, 0, stream>>>(H1, W2l, W2r, b2l, B, H2);
    k_gather<<<gNF, TB, 0, stream>>>(off, nbr, B, H2);

    // ---- SAGE layer 3: H2 -> H1 ----
    k_xform3<HD><<<gXB, TB, 0, stream>>>(H2, W3l, W3r, b3l, B, H1);
    k_gather<<<gNF, TB, 0, stream>>>(off, nbr, B, H1);

    // ---- global mean pool ----
    k_pool2<<<NUM_GRAPHS, TB, 0, stream>>>(goff, H1, cb);

    // ---- MLP head ----
    k_head_gemm3<256><<<64, TB, 0, stream>>>(cb, lin1_w, lin1_b, m1, 64);
    k_bn_tanh3<<<4, TB, 0, stream>>>(m1, g1, be1, 256);
    k_head_gemm3<128><<<32, TB, 0, stream>>>(m1, lin2_w, lin2_b, m2, 256);
    k_bn_tanh3<<<2, TB, 0, stream>>>(m2, g2, be2, 128);
    k_head_gemm3<64><<<16, TB, 0, stream>>>(m2, lin3_w, lin3_b, m3, 128);
    k_bn_tanh3<<<1, TB, 0, stream>>>(m3, g3, be3, 64);
    k_final<<<(NUM_GRAPHS * 10 + TB - 1) / TB, TB, 0, stream>>>(m3, lin4_w, lin4_b, (float*)d_out);
}